// Round 17
// baseline (570.470 us; speedup 1.0000x reference)
//
#include <hip/hip_runtime.h>
#include <hip/hip_bf16.h>

#define NN 100000
#define NE 1600000
#define DD 128
#define GG 64
#define BN_EPS 1e-5f
#define NCOPY 16

#define NBKT 128
#define NPB 782            // nodes per bucket (128*782 = 100096 >= NN)
#define NBLK_A 400
#define EPB 4000           // edges per histogram/scatter block (400*4000 = NE)

typedef unsigned short u16;
typedef unsigned char u8;
using f32x4 = __attribute__((ext_vector_type(4))) float;
using f32x2 = __attribute__((ext_vector_type(2))) float;
using s16x8 = __attribute__((ext_vector_type(8))) short;

__device__ __forceinline__ unsigned enc_f(float v) {
  unsigned u = __float_as_uint(v);
  return (u & 0x80000000u) ? ~u : (u | 0x80000000u);
}
__device__ __forceinline__ float dec_f(unsigned k) {
  unsigned u = (k & 0x80000000u) ? (k & 0x7FFFFFFFu) : ~k;
  return __uint_as_float(u);
}
__device__ __forceinline__ u16 f2b(float x) {
  __hip_bfloat16 h = __float2bfloat16(x);
  return *(u16*)&h;
}
__device__ __forceinline__ float b2f(u16 u) {
  unsigned v = ((unsigned)u) << 16;
  return __uint_as_float(v);
}
__device__ __forceinline__ float blo(unsigned v) { return __uint_as_float(v << 16); }
__device__ __forceinline__ float bhi(unsigned v) { return __uint_as_float(v & 0xFFFF0000u); }

// ---------------- init ----------------
__global__ void k_init(float* stats_raw, float* stats_fin, unsigned* gemb_enc) {
  int i = blockIdx.x * blockDim.x + threadIdx.x;
  if (i < 7 * NCOPY * 256) stats_raw[i] = 0.f;
  if (i < 4 * 256) stats_fin[i] = 0.f;
  if (i < GG*DD) gemb_enc[i] = 0x007FFFFFu;  // enc(-inf)
}

// ---------------- CSR build, level 1: per-block bucket histogram ----------------
__global__ void k_histA(const int* __restrict__ to, int* __restrict__ bh) {
  __shared__ int h[NBKT];
  int t = threadIdx.x, b = blockIdx.x;
  if (t < NBKT) h[t] = 0;
  __syncthreads();
  int e0 = b * EPB;
  for (int i = t; i < EPB; i += 256) {
    int e = e0 + i;
    if (e < NE) atomicAdd(&h[to[e] / NPB], 1);
  }
  __syncthreads();
  if (t < NBKT) bh[t * NBLK_A + b] = h[t];
}

// ---------------- scan of 51200 (bucket,block) counts ----------------
__global__ void k_scanA1(int* data, int* bsum) {   // 50 blocks x 1024
  __shared__ int lds[1024];
  int t = threadIdx.x, i = blockIdx.x * 1024 + t;
  int v = data[i];
  lds[t] = v;
  __syncthreads();
  for (int off = 1; off < 1024; off <<= 1) {
    int a = (t >= off) ? lds[t - off] : 0;
    __syncthreads();
    lds[t] += a;
    __syncthreads();
  }
  data[i] = lds[t] - v;
  if (t == 1023) bsum[blockIdx.x] = lds[t];
}

__global__ void k_scanA2(const int* __restrict__ bsum, int* boff) {  // 1 block x 64
  __shared__ int lds[64];
  int t = threadIdx.x;
  int v = (t < 50) ? bsum[t] : 0;
  lds[t] = v;
  __syncthreads();
  for (int off = 1; off < 64; off <<= 1) {
    int a = (t >= off) ? lds[t - off] : 0;
    __syncthreads();
    lds[t] += a;
    __syncthreads();
  }
  if (t < 50) boff[t] = lds[t] - v;
}

__global__ void k_scanA3(int* data, const int* __restrict__ boff) {  // 50 x 1024
  int i = blockIdx.x * 1024 + threadIdx.x;
  data[i] += boff[blockIdx.x];
}

// ---------------- CSR build, level 2: scatter into bucket-major staging ----------------
__global__ void k_scatter1(const int* __restrict__ to, const int* __restrict__ from,
                           const int* __restrict__ S, int* __restrict__ tmp_dst,
                           uint2* __restrict__ tmp_se) {
  __shared__ int cur[NBKT];
  int t = threadIdx.x, b = blockIdx.x;
  if (t < NBKT) cur[t] = S[t * NBLK_A + b];
  __syncthreads();
  int e0 = b * EPB;
  for (int i = t; i < EPB; i += 256) {
    int e = e0 + i;
    if (e < NE) {
      int n = to[e];
      int p = atomicAdd(&cur[n / NPB], 1);
      tmp_dst[p] = n;
      tmp_se[p] = make_uint2((unsigned)from[e], (unsigned)e);
    }
  }
}

// ---------------- CSR build, level 3: per-bucket counting sort -> row_ptr + csr_src
//                  + fused per-node edge-feature aggregation -> agg4 ----------------
__global__ __launch_bounds__(256)
void k_sort2(const int* __restrict__ S, const int* __restrict__ tmp_dst,
             const uint2* __restrict__ tmp_se, const float* __restrict__ ef,
             int* __restrict__ row_ptr, int* __restrict__ csr_src,
             float* __restrict__ agg4) {
  __shared__ int hist[NPB];
  __shared__ int tsum[256];
  __shared__ float ag0[NPB], ag1[NPB], ag2[NPB];
  const int k = blockIdx.x, t = threadIdx.x;
  const int base = k * NPB;
  const int lo = S[k * NBLK_A];
  const int hi = (k == NBKT - 1) ? NE : S[(k + 1) * NBLK_A];
  for (int j = t; j < NPB; j += 256) {
    hist[j] = 0; ag0[j] = 0.f; ag1[j] = 0.f; ag2[j] = 0.f;
  }
  __syncthreads();
  for (int i = lo + t; i < hi; i += 256)
    atomicAdd(&hist[tmp_dst[i] - base], 1);
  __syncthreads();
  int j0 = t * 4;
  int v0 = (j0 + 0 < NPB) ? hist[j0 + 0] : 0;
  int v1 = (j0 + 1 < NPB) ? hist[j0 + 1] : 0;
  int v2 = (j0 + 2 < NPB) ? hist[j0 + 2] : 0;
  int v3 = (j0 + 3 < NPB) ? hist[j0 + 3] : 0;
  int s = v0 + v1 + v2 + v3;
  tsum[t] = s;
  __syncthreads();
  for (int off = 1; off < 256; off <<= 1) {
    int a = (t >= off) ? tsum[t - off] : 0;
    __syncthreads();
    tsum[t] += a;
    __syncthreads();
  }
  int tb = tsum[t] - s;
  __syncthreads();
  int e0 = lo + tb, e1 = e0 + v0, e2 = e1 + v1, e3 = e2 + v2;
  if (j0 + 0 < NPB) hist[j0 + 0] = e0;
  if (j0 + 1 < NPB) hist[j0 + 1] = e1;
  if (j0 + 2 < NPB) hist[j0 + 2] = e2;
  if (j0 + 3 < NPB) hist[j0 + 3] = e3;
  if (j0 + 0 < NPB && base + j0 + 0 < NN) row_ptr[base + j0 + 0] = e0;
  if (j0 + 1 < NPB && base + j0 + 1 < NN) row_ptr[base + j0 + 1] = e1;
  if (j0 + 2 < NPB && base + j0 + 2 < NN) row_ptr[base + j0 + 2] = e2;
  if (j0 + 3 < NPB && base + j0 + 3 < NN) row_ptr[base + j0 + 3] = e3;
  if (k == NBKT - 1 && t == 0) row_ptr[NN] = NE;
  __syncthreads();
  for (int i = lo + t; i < hi; i += 256) {
    int n = tmp_dst[i];
    uint2 se = tmp_se[i];
    int p = atomicAdd(&hist[n - base], 1);
    csr_src[p] = (int)se.x;
    size_t eb = (size_t)se.y * 3;
    atomicAdd(&ag0[n - base], ef[eb + 0]);
    atomicAdd(&ag1[n - base], ef[eb + 1]);
    atomicAdd(&ag2[n - base], ef[eb + 2]);
  }
  __syncthreads();
#pragma unroll
  for (int jj = 0; jj < 4; ++jj) {
    int j = j0 + jj;
    int n = base + j;
    if (j < NPB && n < NN) {
      int dv = (jj == 0) ? v0 : (jj == 1) ? v1 : (jj == 2) ? v2 : v3;
      ((float4*)agg4)[n] = make_float4(ag0[j], ag1[j], ag2[j], (float)dv);
    }
  }
}

// ---------------- reduce 16 stat copies -> finalized 256 floats ----------------
__global__ void k_redstat(const float* __restrict__ raw, float* __restrict__ fin) {
  int c = threadIdx.x;  // 256
  float s = 0.f;
#pragma unroll
  for (int i = 0; i < NCOPY; ++i) s += raw[i * 256 + c];
  fin[c] = s;
}

// ---------------- neighbor gather: fp8 rows, 4 edges/instr, 8 dims/lane ----------------
__global__ __launch_bounds__(256)
void k_gather(const u8* __restrict__ R8, u16* __restrict__ out,
              const int* __restrict__ row_ptr, const int* __restrict__ csr_src,
              const float* __restrict__ stats, const float* __restrict__ g,
              const float* __restrict__ b) {
  const int wid = (blockIdx.x * 256 + threadIdx.x) >> 6;   // node
  if (wid >= NN) return;
  const int lane = threadIdx.x & 63;
  const int esel = lane >> 4;          // edge slot 0..3
  const int dpos = lane & 15;          // uint2 slot = 8 fp8 dims
  const int s = row_ptr[wid], e = row_ptr[wid + 1];
  const uint2* R2 = (const uint2*)R8;  // row = 16 uint2 (128 fp8)
  f32x2 a01 = {0.f, 0.f}, a23 = {0.f, 0.f}, a45 = {0.f, 0.f}, a67 = {0.f, 0.f};
#define ACC(V)                                                        \
  a01 += __builtin_amdgcn_cvt_pk_f32_fp8((int)V.x, false);            \
  a23 += __builtin_amdgcn_cvt_pk_f32_fp8((int)V.x, true);             \
  a45 += __builtin_amdgcn_cvt_pk_f32_fp8((int)V.y, false);            \
  a67 += __builtin_amdgcn_cvt_pk_f32_fp8((int)V.y, true);
  int i = s;
  for (; i + 15 < e; i += 16) {
    int q0 = csr_src[i      + esel];
    int q1 = csr_src[i + 4  + esel];
    int q2 = csr_src[i + 8  + esel];
    int q3 = csr_src[i + 12 + esel];
    uint2 w0 = R2[(size_t)q0 * 16 + dpos];
    uint2 w1 = R2[(size_t)q1 * 16 + dpos];
    uint2 w2 = R2[(size_t)q2 * 16 + dpos];
    uint2 w3 = R2[(size_t)q3 * 16 + dpos];
    ACC(w0) ACC(w1) ACC(w2) ACC(w3)
  }
  for (; i + 3 < e; i += 4) {
    int q = csr_src[i + esel];
    uint2 wv = R2[(size_t)q * 16 + dpos];
    ACC(wv)
  }
  if (i < e && esel < e - i) {         // tail 1..3 edges
    int q = csr_src[i + esel];
    uint2 wv = R2[(size_t)q * 16 + dpos];
    ACC(wv)
  }
#undef ACC
  float a[8] = {a01.x, a01.y, a23.x, a23.y, a45.x, a45.y, a67.x, a67.y};
#pragma unroll
  for (int j = 0; j < 8; ++j) {
    a[j] += __shfl_xor(a[j], 16);
    a[j] += __shfl_xor(a[j], 32);
  }
  if (esel == 0) {
    const int d0 = dpos * 8;
    float dg = (float)(e - s);
    unsigned pk[4];
#pragma unroll
    for (int h = 0; h < 4; ++h) {
      float r[2];
#pragma unroll
      for (int j = 0; j < 2; ++j) {
        int d = d0 + h * 2 + j;
        float m  = stats[d] * (1.f / NN);
        float vv = stats[DD + d] * (1.f / NN) - m * m;
        float sc = g[d] * rsqrtf(vv + BN_EPS);
        float sh = b[d] - m * sc;
        r[j] = sc * a[h * 2 + j] + sh * dg;
      }
      pk[h] = (unsigned)f2b(r[0]) | ((unsigned)f2b(r[1]) << 16);
    }
    uint4 v; v.x = pk[0]; v.y = pk[1]; v.z = pk[2]; v.w = pk[3];
    ((uint4*)out)[(size_t)wid * 16 + dpos] = v;
  }
}

// ---------------- weight prep ----------------
// MODE 1: in_stats/res_stats are RAW (NCOPY copies) — summed here.
template<int MODE>
__device__ __forceinline__ void wprep_body(
    const float* __restrict__ W, const float* __restrict__ bias,
    const float* __restrict__ in_stats, const float* __restrict__ in_g,
    const float* __restrict__ in_b,
    const float* __restrict__ res_stats, const float* __restrict__ res_g,
    const float* __restrict__ res_b,
    u16* __restrict__ WT, float* __restrict__ biasP, float* __restrict__ rese) {
  __shared__ float s_s[DD], s_t[DD];
  int t = threadIdx.x;
  if (t < DD) {
    float s = 1.f, tt = 0.f;
    if (MODE == 1) {
      float s1 = 0.f, s2 = 0.f, r1 = 0.f, r2 = 0.f;
#pragma unroll
      for (int i = 0; i < NCOPY; ++i) {
        s1 += in_stats[i * 256 + t];
        s2 += in_stats[i * 256 + DD + t];
        r1 += res_stats[i * 256 + t];
        r2 += res_stats[i * 256 + DD + t];
      }
      float mean = s1 * (1.f / NN);
      float var  = s2 * (1.f / NN) - mean * mean;
      float rs = rsqrtf(var + BN_EPS);
      s = in_g[t] * rs;
      tt = in_b[t] - mean * s;
      float m2 = r1 * (1.f / NN);
      float v2 = r2 * (1.f / NN) - m2 * m2;
      float rr = rsqrtf(v2 + BN_EPS);
      float sc = res_g[t] * rr;
      rese[t] = sc;
      rese[DD + t] = res_b[t] - m2 * sc;
    }
    s_s[t] = s; s_t[t] = tt;
  }
  __syncthreads();
  for (int idx = t; idx < DD * DD; idx += 256) {
    int k = idx >> 7, n = idx & 127;
    WT[n * DD + k] = f2b(W[idx] * s_s[k]);
  }
  if (t < DD) {
    float acc = bias[t];
    if (MODE == 1)
      for (int k = 0; k < DD; ++k) acc += s_t[k] * W[k * DD + t];
    biasP[t] = acc;
  }
}

__global__ void k_wprep0(const float* __restrict__ w_n2l_w, const float* __restrict__ w_n2l_b,
                         const float* __restrict__ conv_w, const float* __restrict__ conv_b,
                         u16* wt0, float* bp0, u16* wt1, float* bp1,
                         u16* wt3, float* bp3, u16* wt5, float* bp5) {
  int blk = blockIdx.x;
  const float* W; const float* bias; u16* WT; float* biasP;
  if (blk == 0)      { W = w_n2l_w;              bias = w_n2l_b;          WT = wt0; biasP = bp0; }
  else if (blk == 1) { W = conv_w;               bias = conv_b;           WT = wt1; biasP = bp1; }
  else if (blk == 2) { W = conv_w + DD * DD;     bias = conv_b + DD;      WT = wt3; biasP = bp3; }
  else               { W = conv_w + 2 * DD * DD; bias = conv_b + 2 * DD;  WT = wt5; biasP = bp5; }
  wprep_body<0>(W, bias, nullptr, nullptr, nullptr, nullptr, nullptr, nullptr,
                WT, biasP, nullptr);
}

__global__ void k_wprep1(const float* __restrict__ W, const float* __restrict__ bias,
                         const float* __restrict__ in_stats, const float* __restrict__ in_g,
                         const float* __restrict__ in_b,
                         const float* __restrict__ res_stats, const float* __restrict__ res_g,
                         const float* __restrict__ res_b,
                         u16* WT, float* biasP, float* rese) {
  wprep_body<1>(W, bias, in_stats, in_g, in_b, res_stats, res_g, res_b, WT, biasP, rese);
}

// swizzled LDS byte address: granule XOR within 8-granule (128B) halves of a 256B row
__device__ __forceinline__ int swz_addr(int row_bytes, int xr, int g, int o) {
  return row_bytes + ((((g & 7) ^ xr) | (g & 8)) << 4) + o;
}

// ---------------- MFMA GEMM, 128-row tiles, LDS-staged epilogue (round-13 structure) ----------------
// MODE 0: A bf16 (global_load_lds); e2n via K-extension MFMA from agg4/w_e2l
// MODE 1: A bf16 (global_load_lds); extra = affine(resid); writes fp8 shadow
// MODE 2: A fp32, on-the-fly bf16 cvt; e2n via K-extension MFMA; writes fp8 shadow
template<int MODE>
__global__ __launch_bounds__(256, 2)
void k_gemm(const void* __restrict__ Ain, const u16* __restrict__ WT,
            const float* __restrict__ biasP, u16* __restrict__ out,
            u8* __restrict__ out8,
            float* __restrict__ stats_out,
            const float* __restrict__ rese, const u16* __restrict__ resid,
            const float4* __restrict__ agg4,
            const float* __restrict__ w_e2l, const float* __restrict__ b_e2l) {
  __shared__ __align__(16) u16 lds_a[128 * 128];   // A (swz) -> resid (MODE1)
  __shared__ __align__(16) u16 lds_b[128 * 128];   // WT (swz) -> out staging
  __shared__ float sstats[256];
  const int tid  = threadIdx.x;
  const int lane = tid & 63;
  const int wv   = tid >> 6;
  const int row0 = blockIdx.x * 128;

  sstats[tid] = 0.f;

  // ---- stage WT and A ----
#pragma unroll
  for (int c = 0; c < 8; ++c) {
    int gidx = (wv * 8 + c) * 64 + lane;
    int row = gidx >> 4, gL = gidx & 15;
    int gS = (gL & 8) | ((gL & 7) ^ (row & 7));
    const u16* gsrcB = WT + (size_t)row * DD + gS * 8;
    u16* ldstB = lds_b + (size_t)(wv * 8 + c) * 512;
    __builtin_amdgcn_global_load_lds(
        (const __attribute__((address_space(1))) unsigned int*)gsrcB,
        (__attribute__((address_space(3))) unsigned int*)ldstB, 16, 0, 0);
    if (MODE != 2) {
      int arow = row0 + row; if (arow >= NN) arow = NN - 1;
      const u16* gsrcA = (const u16*)Ain + (size_t)arow * DD + gS * 8;
      u16* ldstA = lds_a + (size_t)(wv * 8 + c) * 512;
      __builtin_amdgcn_global_load_lds(
          (const __attribute__((address_space(1))) unsigned int*)gsrcA,
          (__attribute__((address_space(3))) unsigned int*)ldstA, 16, 0, 0);
    }
  }
  if (MODE == 2) {
    const float2* Af = (const float2*)Ain;       // row = 64 float2 (128 f32)
#pragma unroll
    for (int k = 0; k < 32; ++k) {
      int idx = k * 256 + tid;                   // 0..8191
      int r = idx >> 6, ln = idx & 63;
      int n = row0 + r; if (n >= NN) n = NN - 1;
      float2 v = Af[(size_t)n * 64 + ln];
      unsigned pk = (unsigned)f2b(v.x) | ((unsigned)f2b(v.y) << 16);
      int gLn = ln >> 2, oin = (ln & 3) * 4;
      int gS = (gLn & 8) | ((gLn & 7) ^ (r & 7));
      *(unsigned*)((char*)lds_a + r * 256 + gS * 16 + oin) = pk;
    }
  }
  __syncthreads();

  const int colid = lane & 15;
  const int lgrp  = lane >> 4;
  const int rowbase = wv * 32;
  const int o = (lgrp & 1) * 8;

  // ---- A fragments for this wave's 32 rows ----
  s16x8 afr[2][4];
#pragma unroll
  for (int rf = 0; rf < 2; ++rf) {
    int r = rowbase + rf * 16 + colid;
    int rb = r << 8, xr = r & 7;
#pragma unroll
    for (int ks = 0; ks < 4; ++ks) {
      int g0 = ks * 4 + (lgrp >> 1);
      uint2 lo = *(const uint2*)((const char*)lds_a + swz_addr(rb, xr, g0, o));
      uint2 hi = *(const uint2*)((const char*)lds_a + swz_addr(rb, xr, g0 + 2, o));
      union { unsigned u[4]; s16x8 v; } pk;
      pk.u[0] = lo.x; pk.u[1] = lo.y; pk.u[2] = hi.x; pk.u[3] = hi.y;
      afr[rf][ks] = pk.v;
    }
  }

  // ext A fragments: k=0..3 = agg4[row] on lgrp==0 lanes (MODE 0/2)
  s16x8 aext[2];
  if (MODE != 1) {
#pragma unroll
    for (int rf = 0; rf < 2; ++rf) {
      int r = row0 + rowbase + rf * 16 + colid;
      if (r >= NN) r = NN - 1;
      float4 a4 = agg4[r];
      union { unsigned u[4]; s16x8 v; } pk;
      pk.u[0] = (lgrp == 0) ? ((unsigned)f2b(a4.x) | ((unsigned)f2b(a4.y) << 16)) : 0u;
      pk.u[1] = (lgrp == 0) ? ((unsigned)f2b(a4.z) | ((unsigned)f2b(a4.w) << 16)) : 0u;
      pk.u[2] = 0u; pk.u[3] = 0u;
      aext[rf] = pk.v;
    }
  }

  // ---- stage resid into lds_a (overlaps MFMA burst); barrier only needed here ----
  if (MODE == 1) {
    __syncthreads();  // all waves done reading lds_a before overwrite
#pragma unroll
    for (int c = 0; c < 8; ++c) {
      int gidx = (wv * 8 + c) * 64 + lane;
      int row = gidx >> 4, gL = gidx & 15;
      int gS = (gL & 8) | ((gL & 7) ^ (row & 7));
      int arow = row0 + row; if (arow >= NN) arow = NN - 1;
      const u16* gsrcR = resid + (size_t)arow * DD + gS * 8;
      u16* ldstR = lds_a + (size_t)(wv * 8 + c) * 512;
      __builtin_amdgcn_global_load_lds(
          (const __attribute__((address_space(1))) unsigned int*)gsrcR,
          (__attribute__((address_space(3))) unsigned int*)ldstR, 16, 0, 0);
    }
  }

  // ---- compute: all 8 column-fragments in registers ----
  f32x4 acc[2][8];
#pragma unroll
  for (int cf = 0; cf < 8; ++cf) {
    const int col = cf * 16 + colid;
    const float bp = biasP[col];
    acc[0][cf] = (f32x4){bp, bp, bp, bp};
    acc[1][cf] = (f32x4){bp, bp, bp, bp};
    int nb = col << 8, xn = col & 7;
#pragma unroll
    for (int ks = 0; ks < 4; ++ks) {
      int g0 = ks * 4 + (lgrp >> 1);
      uint2 lo = *(const uint2*)((const char*)lds_b + swz_addr(nb, xn, g0, o));
      uint2 hi = *(const uint2*)((const char*)lds_b + swz_addr(nb, xn, g0 + 2, o));
      union { unsigned u[4]; s16x8 v; } pk;
      pk.u[0] = lo.x; pk.u[1] = lo.y; pk.u[2] = hi.x; pk.u[3] = hi.y;
      acc[0][cf] = __builtin_amdgcn_mfma_f32_16x16x32_bf16(afr[0][ks], pk.v, acc[0][cf], 0, 0, 0);
      acc[1][cf] = __builtin_amdgcn_mfma_f32_16x16x32_bf16(afr[1][ks], pk.v, acc[1][cf], 0, 0, 0);
    }
    if (MODE != 1) {
      union { unsigned u[4]; s16x8 v; } bx;
      if (lgrp == 0) {
        float w0 = w_e2l[col], w1 = w_e2l[DD + col];
        float w2 = w_e2l[2 * DD + col], be = b_e2l[col];
        bx.u[0] = (unsigned)f2b(w0) | ((unsigned)f2b(w1) << 16);
        bx.u[1] = (unsigned)f2b(w2) | ((unsigned)f2b(be) << 16);
      } else { bx.u[0] = 0u; bx.u[1] = 0u; }
      bx.u[2] = 0u; bx.u[3] = 0u;
      acc[0][cf] = __builtin_amdgcn_mfma_f32_16x16x32_bf16(aext[0], bx.v, acc[0][cf], 0, 0, 0);
      acc[1][cf] = __builtin_amdgcn_mfma_f32_16x16x32_bf16(aext[1], bx.v, acc[1][cf], 0, 0, 0);
    }
  }
  __syncthreads();  // resid arrived (vmcnt drained by barrier); all B reads done

  // ---- epilogue: extra + relu + stats, staged into lds_b ----
#pragma unroll
  for (int cf = 0; cf < 8; ++cf) {
    const int col = cf * 16 + colid;
    float sc, sh;
    if (MODE == 1) { sc = rese[col]; sh = rese[DD + col]; }
    float s = 0.f, s2 = 0.f;
    int gc = col >> 3, cb = (col & 7) * 2;
#pragma unroll
    for (int rf = 0; rf < 2; ++rf)
#pragma unroll
      for (int q = 0; q < 4; ++q) {
        int rloc = rowbase + rf * 16 + lgrp * 4 + q;
        int r = row0 + rloc;
        float v = acc[rf][cf][q];
        if (MODE == 1) {
          int gsr = (gc & 8) | ((gc & 7) ^ (rloc & 7));
          u16 rv = *(const u16*)((const char*)lds_a + rloc * 256 + gsr * 16 + cb);
          v += sc * b2f(rv) + sh;
        }
        v = fmaxf(v, 0.f);
        if (r < NN) { s += v; s2 += v * v; }
        int gso = (gc & 8) | ((gc & 7) ^ (rloc & 7));
        *(u16*)((char*)lds_b + rloc * 256 + gso * 16 + cb) = f2b(v);
      }
    s  += __shfl_xor(s, 16);  s  += __shfl_xor(s, 32);
    s2 += __shfl_xor(s2, 16); s2 += __shfl_xor(s2, 32);
    if (lgrp == 0) {
      atomicAdd(&sstats[col], s);
      atomicAdd(&sstats[DD + col], s2);
    }
  }
  __syncthreads();

  // ---- coalesced store from lds_b (+ fp8 shadow for gathered buffers) ----
#pragma unroll
  for (int k = 0; k < 8; ++k) {
    int idx = k * 256 + tid;          // 0..2047
    int r = idx >> 4, g = idx & 15;
    if (row0 + r < NN) {
      int gd = (g & 8) | ((g & 7) ^ (r & 7));   // data granule stored at slot g
      uint4 v = *(const uint4*)((const char*)lds_b + r * 256 + g * 16);
      *(uint4*)(out + (size_t)(row0 + r) * DD + gd * 8) = v;
      if (MODE != 0) {
        int p0 = 0, p1 = 0;
        p0 = __builtin_amdgcn_cvt_pk_fp8_f32(blo(v.x), bhi(v.x), p0, false);
        p0 = __builtin_amdgcn_cvt_pk_fp8_f32(blo(v.y), bhi(v.y), p0, true);
        p1 = __builtin_amdgcn_cvt_pk_fp8_f32(blo(v.z), bhi(v.z), p1, false);
        p1 = __builtin_amdgcn_cvt_pk_fp8_f32(blo(v.w), bhi(v.w), p1, true);
        uint2 o8; o8.x = (unsigned)p0; o8.y = (unsigned)p1;
        *(uint2*)(out8 + (size_t)(row0 + r) * DD + gd * 8) = o8;
      }
    }
  }
  atomicAdd(&stats_out[(blockIdx.x & (NCOPY - 1)) * 256 + tid], sstats[tid]);
}

// ---------------- segment max (bf16 input) ----------------
__global__ void k_segmax(const u16* __restrict__ R, const int* __restrict__ g_idx,
                         unsigned* __restrict__ gemb_enc,
                         const float* __restrict__ stats, const float* __restrict__ g,
                         const float* __restrict__ b) {
  int t = blockIdx.x * blockDim.x + threadIdx.x;
  int d = t & (DD - 1);
  int chunk = t >> 7;
  int n0 = chunk * 8;
  if (n0 >= NN) return;
  float mean = stats[d] * (1.f / NN);
  float var  = stats[DD + d] * (1.f / NN) - mean * mean;
  float rs = rsqrtf(var + BN_EPS);
  float scale = g[d] * rs;
  float shift = b[d] - mean * scale;
  int cur = -1; float run = 0.f;
  int nend = n0 + 8; if (nend > NN) nend = NN;
  for (int n = n0; n < nend; ++n) {
    float v = scale * b2f(R[(size_t)n * DD + d]) + shift;
    int gi = g_idx[n];
    if (gi != cur) {
      if (cur >= 0) atomicMax(&gemb_enc[cur * DD + d], enc_f(run));
      cur = gi; run = v;
    } else {
      run = fmaxf(run, v);
    }
  }
  if (cur >= 0) atomicMax(&gemb_enc[cur * DD + d], enc_f(run));
}

// ---------------- readout ----------------
__global__ void k_readout(const unsigned* __restrict__ gemb,
                          const float* __restrict__ W, const float* __restrict__ b,
                          float* __restrict__ out) {
  __shared__ float row[DD];
  int g = blockIdx.x, t = threadIdx.x;
  row[t] = dec_f(gemb[g * DD + t]);
  __syncthreads();
  float acc = b[t];
  for (int d = 0; d < DD; ++d) acc += row[d] * W[d * DD + t];
  out[g * DD + t] = fmaxf(acc, 0.f);
}

extern "C" void kernel_launch(void* const* d_in, const int* in_sizes, int n_in,
                              void* d_out, int out_size, void* d_ws, size_t ws_size,
                              hipStream_t stream) {
  const float* node_feat = (const float*)d_in[0];
  const float* edge_feat = (const float*)d_in[1];
  const int*   efrom     = (const int*)d_in[2];
  const int*   eto       = (const int*)d_in[3];
  const int*   g_idx     = (const int*)d_in[4];
  const float* w_n2l_w   = (const float*)d_in[6];
  const float* w_n2l_b   = (const float*)d_in[7];
  const float* w_e2l_w   = (const float*)d_in[8];   // [4][3][128]
  const float* w_e2l_b   = (const float*)d_in[9];   // [4][128]
  const float* conv_w    = (const float*)d_in[10];  // [3][128][128]
  const float* conv_b    = (const float*)d_in[11];
  const float* l2_w      = (const float*)d_in[12];
  const float* l2_b      = (const float*)d_in[13];
  const float* msg_bn_g  = (const float*)d_in[14];  // [4][128]
  const float* msg_bn_b  = (const float*)d_in[15];
  const float* hid_bn_g  = (const float*)d_in[16];  // [3][128]
  const float* hid_bn_b  = (const float*)d_in[17];
  const float* readout_w = (const float*)d_in[18];
  const float* readout_b = (const float*)d_in[19];
  float* out = (float*)d_out;
  (void)in_sizes; (void)n_in; (void)out_size; (void)ws_size;

  char* ws = (char*)d_ws;
  size_t off = 0;
  auto alloc = [&](size_t bytes) -> void* {
    void* p = ws + off; off += (bytes + 511) & ~(size_t)511; return p;
  };
  u16*      Pb0     = (u16*)alloc((size_t)NN * DD * 2);
  u16*      Pb1     = (u16*)alloc((size_t)NN * DD * 2);
  u16*      Pb2     = (u16*)alloc((size_t)NN * DD * 2);   // also CSR staging scratch
  u8*       P8a     = (u8*)alloc((size_t)NN * DD);        // fp8 shadow of Pb0-chain
  u8*       P8b     = (u8*)alloc((size_t)NN * DD);        // fp8 shadow of Pb1-chain
  float*    agg4    = (float*)alloc((size_t)NN * 4 * 4);
  int*      row_ptr = (int*)alloc((size_t)(NN + 1) * 4);
  int*      csr_src = (int*)alloc((size_t)NE * 4);
  int*      S       = (int*)alloc((size_t)NBKT * NBLK_A * 4);  // 51200
  int*      bsumA   = (int*)alloc((size_t)64 * 4);
  int*      boffA   = (int*)alloc((size_t)64 * 4);
  float*    stats   = (float*)alloc((size_t)7 * NCOPY * 256 * 4);  // raw copies
  float*    statfin = (float*)alloc((size_t)4 * 256 * 4);          // finalized msg stats
  unsigned* gemb    = (unsigned*)alloc((size_t)GG * DD * 4);
  u16*      wt[7];
  float*    bp[7];
  float*    re[7];
  for (int i = 0; i < 7; ++i) {
    wt[i] = (u16*)alloc((size_t)DD * DD * 2);
    bp[i] = (float*)alloc((size_t)DD * 4);
    re[i] = (float*)alloc((size_t)2 * DD * 4);
  }
  // CSR staging aliases Pb2 (dead until the first conv GEMM)
  int*   tmp_dst = (int*)Pb2;                       // 6.4 MB
  uint2* tmp_se  = (uint2*)((char*)Pb2 + (size_t)NE * 4);  // 12.8 MB (<= 25.6 total)

  k_init<<<(NN + 255) / 256, 256, 0, stream>>>(stats, statfin, gemb);
  k_histA<<<NBLK_A, 256, 0, stream>>>(eto, S);
  k_scanA1<<<50, 1024, 0, stream>>>(S, bsumA);
  k_scanA2<<<1, 64, 0, stream>>>(bsumA, boffA);
  k_scanA3<<<50, 1024, 0, stream>>>(S, boffA);
  k_scatter1<<<NBLK_A, 256, 0, stream>>>(eto, efrom, S, tmp_dst, tmp_se);
  k_sort2<<<NBKT, 256, 0, stream>>>(S, tmp_dst, tmp_se, edge_feat, row_ptr,
                                    csr_src, agg4);
  k_wprep0<<<4, 256, 0, stream>>>(w_n2l_w, w_n2l_b, conv_w, conv_b,
                                  wt[0], bp[0], wt[1], bp[1], wt[3], bp[3], wt[5], bp[5]);

  // raw stat buffers: [msg0..msg3, hid0..hid2] x (NCOPY*256)
  float* msg_raw[4] = { stats + 0*NCOPY*256, stats + 1*NCOPY*256,
                        stats + 2*NCOPY*256, stats + 3*NCOPY*256 };
  float* hid_raw[3] = { stats + 4*NCOPY*256, stats + 5*NCOPY*256, stats + 6*NCOPY*256 };
  float* msg_fin[4] = { statfin, statfin + 256, statfin + 512, statfin + 768 };
  const int GEMM_GRID = (NN + 127) / 128;  // 782

  // GEMM0 (MODE 2): Pb0 = relu(bf16(node_feat) @ w_n2l + b + e2n0); fp8 shadow P8a
  k_gemm<2><<<GEMM_GRID, 256, 0, stream>>>(node_feat, wt[0], bp[0], Pb0, P8a, msg_raw[0],
      nullptr, nullptr, (const float4*)agg4, w_e2l_w + 0 * 3 * DD, w_e2l_b + 0 * DD);
  k_redstat<<<1, 256, 0, stream>>>(msg_raw[0], msg_fin[0]);

  u16* R = Pb0; u16* other = Pb1;
  u8*  R8 = P8a; u8* other8 = P8b;
  for (int lv = 0; lv < 3; ++lv) {
    int wc = 1 + 2 * lv, wl = 2 + 2 * lv;
    // agg = affine_msg[lv](seg(R[from])) -> other (reads fp8 shadow of R)
    k_gather<<<(NN * 64 + 255) / 256, 256, 0, stream>>>(R8, other, row_ptr, csr_src,
        msg_fin[lv], msg_bn_g + lv * DD, msg_bn_b + lv * DD);
    // conv (MODE 0): Pb2 = relu(other @ conv_w[lv] + conv_b + e2n[lv+1]); raw -> hid[lv]
    k_gemm<0><<<GEMM_GRID, 256, 0, stream>>>(other, wt[wc], bp[wc], Pb2, nullptr,
        hid_raw[lv], nullptr, nullptr, (const float4*)agg4,
        w_e2l_w + (size_t)(lv + 1) * 3 * DD, w_e2l_b + (lv + 1) * DD);
    // l2 (MODE 1): other = relu(norm_hid(Pb2) @ l2_w[lv] + l2_b + affine_msg[lv](R))
    k_wprep1<<<1, 256, 0, stream>>>(l2_w + (size_t)lv * DD * DD, l2_b + lv * DD,
        hid_raw[lv], hid_bn_g + lv * DD, hid_bn_b + lv * DD,
        msg_raw[lv], msg_bn_g + lv * DD, msg_bn_b + lv * DD, wt[wl], bp[wl], re[wl]);
    k_gemm<1><<<GEMM_GRID, 256, 0, stream>>>(Pb2, wt[wl], bp[wl], other, other8,
        msg_raw[lv + 1], re[wl], R, nullptr, nullptr, nullptr);
    k_redstat<<<1, 256, 0, stream>>>(msg_raw[lv + 1], msg_fin[lv + 1]);
    u16* t = R; R = other; other = t;
    u8*  t8 = R8; R8 = other8; other8 = t8;
  }

  k_segmax<<<(NN / 8) * DD / 256, 256, 0, stream>>>(
      R, g_idx, gemb, msg_fin[3], msg_bn_g + 3 * DD, msg_bn_b + 3 * DD);
  k_readout<<<GG, DD, 0, stream>>>(gemb, readout_w, readout_b, out);
}

// Round 18
// 551.376 us; speedup vs baseline: 1.0346x; 1.0346x over previous
//
#include <hip/hip_runtime.h>
#include <hip/hip_bf16.h>

#define NN 100000
#define NE 1600000
#define DD 128
#define GG 64
#define BN_EPS 1e-5f
#define NCOPY 16

#define NBKT 512
#define NPB 196            // nodes per bucket (512*196 = 100352 >= NN)
#define NBLK_A 400
#define EPB 4000           // edges per histogram/scatter block (400*4000 = NE)
#define NSCAN (NBKT * NBLK_A / 1024)   // 200 scan blocks

typedef unsigned short u16;
typedef unsigned char u8;
using f32x4 = __attribute__((ext_vector_type(4))) float;
using f32x2 = __attribute__((ext_vector_type(2))) float;
using s16x8 = __attribute__((ext_vector_type(8))) short;

__device__ __forceinline__ unsigned enc_f(float v) {
  unsigned u = __float_as_uint(v);
  return (u & 0x80000000u) ? ~u : (u | 0x80000000u);
}
__device__ __forceinline__ float dec_f(unsigned k) {
  unsigned u = (k & 0x80000000u) ? (k & 0x7FFFFFFFu) : ~k;
  return __uint_as_float(u);
}
__device__ __forceinline__ u16 f2b(float x) {
  __hip_bfloat16 h = __float2bfloat16(x);
  return *(u16*)&h;
}
__device__ __forceinline__ float b2f(u16 u) {
  unsigned v = ((unsigned)u) << 16;
  return __uint_as_float(v);
}
__device__ __forceinline__ float blo(unsigned v) { return __uint_as_float(v << 16); }
__device__ __forceinline__ float bhi(unsigned v) { return __uint_as_float(v & 0xFFFF0000u); }

// ---------------- init ----------------
__global__ void k_init(float* stats_raw, float* stats_fin, unsigned* gemb_enc) {
  int i = blockIdx.x * blockDim.x + threadIdx.x;
  if (i < 7 * NCOPY * 256) stats_raw[i] = 0.f;
  if (i < 4 * 256) stats_fin[i] = 0.f;
  if (i < GG*DD) gemb_enc[i] = 0x007FFFFFu;  // enc(-inf)
}

// ---------------- CSR build, level 1: per-block bucket histogram ----------------
__global__ void k_histA(const int* __restrict__ to, int* __restrict__ bh) {
  __shared__ int h[NBKT];
  int t = threadIdx.x, b = blockIdx.x;
  for (int j = t; j < NBKT; j += 256) h[j] = 0;
  __syncthreads();
  int e0 = b * EPB;
  for (int i = t; i < EPB; i += 256) {
    int e = e0 + i;
    if (e < NE) atomicAdd(&h[to[e] / NPB], 1);
  }
  __syncthreads();
  for (int j = t; j < NBKT; j += 256) bh[j * NBLK_A + b] = h[j];
}

// ---------------- scan of NBKT*NBLK_A (bucket,block) counts ----------------
__global__ void k_scanA1(int* data, int* bsum) {   // NSCAN blocks x 1024
  __shared__ int lds[1024];
  int t = threadIdx.x, i = blockIdx.x * 1024 + t;
  int v = data[i];
  lds[t] = v;
  __syncthreads();
  for (int off = 1; off < 1024; off <<= 1) {
    int a = (t >= off) ? lds[t - off] : 0;
    __syncthreads();
    lds[t] += a;
    __syncthreads();
  }
  data[i] = lds[t] - v;
  if (t == 1023) bsum[blockIdx.x] = lds[t];
}

__global__ void k_scanA2(const int* __restrict__ bsum, int* boff) {  // 1 block x 256
  __shared__ int lds[256];
  int t = threadIdx.x;
  int v = (t < NSCAN) ? bsum[t] : 0;
  lds[t] = v;
  __syncthreads();
  for (int off = 1; off < 256; off <<= 1) {
    int a = (t >= off) ? lds[t - off] : 0;
    __syncthreads();
    lds[t] += a;
    __syncthreads();
  }
  if (t < NSCAN) boff[t] = lds[t] - v;
}

__global__ void k_scanA3(int* data, const int* __restrict__ boff) {  // NSCAN x 1024
  int i = blockIdx.x * 1024 + threadIdx.x;
  data[i] += boff[blockIdx.x];
}

// ---------------- CSR build, level 2: scatter into bucket-major staging ----------------
__global__ void k_scatter1(const int* __restrict__ to, const int* __restrict__ from,
                           const int* __restrict__ S, int* __restrict__ tmp_dst,
                           uint2* __restrict__ tmp_se) {
  __shared__ int cur[NBKT];
  int t = threadIdx.x, b = blockIdx.x;
  for (int j = t; j < NBKT; j += 256) cur[j] = S[j * NBLK_A + b];
  __syncthreads();
  int e0 = b * EPB;
  for (int i = t; i < EPB; i += 256) {
    int e = e0 + i;
    if (e < NE) {
      int n = to[e];
      int p = atomicAdd(&cur[n / NPB], 1);
      tmp_dst[p] = n;
      tmp_se[p] = make_uint2((unsigned)from[e], (unsigned)e);
    }
  }
}

// ---------------- CSR build, level 3: per-bucket counting sort -> row_ptr + csr_src
//                  + fused per-node edge-feature aggregation -> agg4 ----------------
__global__ __launch_bounds__(256)
void k_sort2(const int* __restrict__ S, const int* __restrict__ tmp_dst,
             const uint2* __restrict__ tmp_se, const float* __restrict__ ef,
             int* __restrict__ row_ptr, int* __restrict__ csr_src,
             float* __restrict__ agg4) {
  __shared__ int hist[NPB];
  __shared__ int tsum[256];
  __shared__ float ag0[NPB], ag1[NPB], ag2[NPB];
  const int k = blockIdx.x, t = threadIdx.x;
  const int base = k * NPB;
  const int lo = S[k * NBLK_A];
  const int hi = (k == NBKT - 1) ? NE : S[(k + 1) * NBLK_A];
  if (t < NPB) { hist[t] = 0; ag0[t] = 0.f; ag1[t] = 0.f; ag2[t] = 0.f; }
  __syncthreads();
  for (int i = lo + t; i < hi; i += 256)
    atomicAdd(&hist[tmp_dst[i] - base], 1);
  __syncthreads();
  int v = (t < NPB) ? hist[t] : 0;
  tsum[t] = v;
  __syncthreads();
  for (int off = 1; off < 256; off <<= 1) {
    int a = (t >= off) ? tsum[t - off] : 0;
    __syncthreads();
    tsum[t] += a;
    __syncthreads();
  }
  int e0 = lo + tsum[t] - v;
  __syncthreads();
  if (t < NPB) {
    hist[t] = e0;
    if (base + t < NN) row_ptr[base + t] = e0;
  }
  if (k == NBKT - 1 && t == 0) row_ptr[NN] = NE;
  __syncthreads();
  for (int i = lo + t; i < hi; i += 256) {
    int n = tmp_dst[i];
    uint2 se = tmp_se[i];
    int p = atomicAdd(&hist[n - base], 1);
    csr_src[p] = (int)se.x;
    size_t eb = (size_t)se.y * 3;
    atomicAdd(&ag0[n - base], ef[eb + 0]);
    atomicAdd(&ag1[n - base], ef[eb + 1]);
    atomicAdd(&ag2[n - base], ef[eb + 2]);
  }
  __syncthreads();
  if (t < NPB && base + t < NN)
    ((float4*)agg4)[base + t] = make_float4(ag0[t], ag1[t], ag2[t], (float)v);
}

// ---------------- reduce 16 stat copies -> finalized 256 floats ----------------
__global__ void k_redstat(const float* __restrict__ raw, float* __restrict__ fin) {
  int c = threadIdx.x;  // 256
  float s = 0.f;
#pragma unroll
  for (int i = 0; i < NCOPY; ++i) s += raw[i * 256 + c];
  fin[c] = s;
}

// ---------------- neighbor gather: fp8 rows, 4 edges/instr, 8 dims/lane ----------------
__global__ __launch_bounds__(256)
void k_gather(const u8* __restrict__ R8, u16* __restrict__ out,
              const int* __restrict__ row_ptr, const int* __restrict__ csr_src,
              const float* __restrict__ stats, const float* __restrict__ g,
              const float* __restrict__ b) {
  const int wid = (blockIdx.x * 256 + threadIdx.x) >> 6;   // node
  if (wid >= NN) return;
  const int lane = threadIdx.x & 63;
  const int esel = lane >> 4;          // edge slot 0..3
  const int dpos = lane & 15;          // uint2 slot = 8 fp8 dims
  const int s = row_ptr[wid], e = row_ptr[wid + 1];
  const uint2* R2 = (const uint2*)R8;  // row = 16 uint2 (128 fp8)
  f32x2 a01 = {0.f, 0.f}, a23 = {0.f, 0.f}, a45 = {0.f, 0.f}, a67 = {0.f, 0.f};
#define ACC(V)                                                        \
  a01 += __builtin_amdgcn_cvt_pk_f32_fp8((int)V.x, false);            \
  a23 += __builtin_amdgcn_cvt_pk_f32_fp8((int)V.x, true);             \
  a45 += __builtin_amdgcn_cvt_pk_f32_fp8((int)V.y, false);            \
  a67 += __builtin_amdgcn_cvt_pk_f32_fp8((int)V.y, true);
  int i = s;
  for (; i + 15 < e; i += 16) {
    int q0 = csr_src[i      + esel];
    int q1 = csr_src[i + 4  + esel];
    int q2 = csr_src[i + 8  + esel];
    int q3 = csr_src[i + 12 + esel];
    uint2 w0 = R2[(size_t)q0 * 16 + dpos];
    uint2 w1 = R2[(size_t)q1 * 16 + dpos];
    uint2 w2 = R2[(size_t)q2 * 16 + dpos];
    uint2 w3 = R2[(size_t)q3 * 16 + dpos];
    ACC(w0) ACC(w1) ACC(w2) ACC(w3)
  }
  for (; i + 3 < e; i += 4) {
    int q = csr_src[i + esel];
    uint2 wv = R2[(size_t)q * 16 + dpos];
    ACC(wv)
  }
  if (i < e && esel < e - i) {         // tail 1..3 edges
    int q = csr_src[i + esel];
    uint2 wv = R2[(size_t)q * 16 + dpos];
    ACC(wv)
  }
#undef ACC
  float a[8] = {a01.x, a01.y, a23.x, a23.y, a45.x, a45.y, a67.x, a67.y};
#pragma unroll
  for (int j = 0; j < 8; ++j) {
    a[j] += __shfl_xor(a[j], 16);
    a[j] += __shfl_xor(a[j], 32);
  }
  if (esel == 0) {
    const int d0 = dpos * 8;
    float dg = (float)(e - s);
    unsigned pk[4];
#pragma unroll
    for (int h = 0; h < 4; ++h) {
      float r[2];
#pragma unroll
      for (int j = 0; j < 2; ++j) {
        int d = d0 + h * 2 + j;
        float m  = stats[d] * (1.f / NN);
        float vv = stats[DD + d] * (1.f / NN) - m * m;
        float sc = g[d] * rsqrtf(vv + BN_EPS);
        float sh = b[d] - m * sc;
        r[j] = sc * a[h * 2 + j] + sh * dg;
      }
      pk[h] = (unsigned)f2b(r[0]) | ((unsigned)f2b(r[1]) << 16);
    }
    uint4 v; v.x = pk[0]; v.y = pk[1]; v.z = pk[2]; v.w = pk[3];
    ((uint4*)out)[(size_t)wid * 16 + dpos] = v;
  }
}

// ---------------- weight prep ----------------
// MODE 1: in_stats/res_stats are RAW (NCOPY copies) — summed here.
template<int MODE>
__device__ __forceinline__ void wprep_body(
    const float* __restrict__ W, const float* __restrict__ bias,
    const float* __restrict__ in_stats, const float* __restrict__ in_g,
    const float* __restrict__ in_b,
    const float* __restrict__ res_stats, const float* __restrict__ res_g,
    const float* __restrict__ res_b,
    u16* __restrict__ WT, float* __restrict__ biasP, float* __restrict__ rese) {
  __shared__ float s_s[DD], s_t[DD];
  int t = threadIdx.x;
  if (t < DD) {
    float s = 1.f, tt = 0.f;
    if (MODE == 1) {
      float s1 = 0.f, s2 = 0.f, r1 = 0.f, r2 = 0.f;
#pragma unroll
      for (int i = 0; i < NCOPY; ++i) {
        s1 += in_stats[i * 256 + t];
        s2 += in_stats[i * 256 + DD + t];
        r1 += res_stats[i * 256 + t];
        r2 += res_stats[i * 256 + DD + t];
      }
      float mean = s1 * (1.f / NN);
      float var  = s2 * (1.f / NN) - mean * mean;
      float rs = rsqrtf(var + BN_EPS);
      s = in_g[t] * rs;
      tt = in_b[t] - mean * s;
      float m2 = r1 * (1.f / NN);
      float v2 = r2 * (1.f / NN) - m2 * m2;
      float rr = rsqrtf(v2 + BN_EPS);
      float sc = res_g[t] * rr;
      rese[t] = sc;
      rese[DD + t] = res_b[t] - m2 * sc;
    }
    s_s[t] = s; s_t[t] = tt;
  }
  __syncthreads();
  for (int idx = t; idx < DD * DD; idx += 256) {
    int k = idx >> 7, n = idx & 127;
    WT[n * DD + k] = f2b(W[idx] * s_s[k]);
  }
  if (t < DD) {
    float acc = bias[t];
    if (MODE == 1)
      for (int k = 0; k < DD; ++k) acc += s_t[k] * W[k * DD + t];
    biasP[t] = acc;
  }
}

__global__ void k_wprep0(const float* __restrict__ w_n2l_w, const float* __restrict__ w_n2l_b,
                         const float* __restrict__ conv_w, const float* __restrict__ conv_b,
                         u16* wt0, float* bp0, u16* wt1, float* bp1,
                         u16* wt3, float* bp3, u16* wt5, float* bp5) {
  int blk = blockIdx.x;
  const float* W; const float* bias; u16* WT; float* biasP;
  if (blk == 0)      { W = w_n2l_w;              bias = w_n2l_b;          WT = wt0; biasP = bp0; }
  else if (blk == 1) { W = conv_w;               bias = conv_b;           WT = wt1; biasP = bp1; }
  else if (blk == 2) { W = conv_w + DD * DD;     bias = conv_b + DD;      WT = wt3; biasP = bp3; }
  else               { W = conv_w + 2 * DD * DD; bias = conv_b + 2 * DD;  WT = wt5; biasP = bp5; }
  wprep_body<0>(W, bias, nullptr, nullptr, nullptr, nullptr, nullptr, nullptr,
                WT, biasP, nullptr);
}

__global__ void k_wprep1(const float* __restrict__ W, const float* __restrict__ bias,
                         const float* __restrict__ in_stats, const float* __restrict__ in_g,
                         const float* __restrict__ in_b,
                         const float* __restrict__ res_stats, const float* __restrict__ res_g,
                         const float* __restrict__ res_b,
                         u16* WT, float* biasP, float* rese) {
  wprep_body<1>(W, bias, in_stats, in_g, in_b, res_stats, res_g, res_b, WT, biasP, rese);
}

// swizzled LDS byte address: granule XOR within 8-granule (128B) halves of a 256B row
__device__ __forceinline__ int swz_addr(int row_bytes, int xr, int g, int o) {
  return row_bytes + ((((g & 7) ^ xr) | (g & 8)) << 4) + o;
}

// ---------------- MFMA GEMM, 128-row tiles, LDS-staged epilogue (round-13 structure) ----------------
// MODE 0: A bf16 (global_load_lds); e2n via K-extension MFMA from agg4/w_e2l
// MODE 1: A bf16 (global_load_lds); extra = affine(resid); writes fp8 shadow
// MODE 2: A fp32, on-the-fly bf16 cvt; e2n via K-extension MFMA; writes fp8 shadow
template<int MODE>
__global__ __launch_bounds__(256, 2)
void k_gemm(const void* __restrict__ Ain, const u16* __restrict__ WT,
            const float* __restrict__ biasP, u16* __restrict__ out,
            u8* __restrict__ out8,
            float* __restrict__ stats_out,
            const float* __restrict__ rese, const u16* __restrict__ resid,
            const float4* __restrict__ agg4,
            const float* __restrict__ w_e2l, const float* __restrict__ b_e2l) {
  __shared__ __align__(16) u16 lds_a[128 * 128];   // A (swz) -> resid (MODE1)
  __shared__ __align__(16) u16 lds_b[128 * 128];   // WT (swz) -> out staging
  __shared__ float sstats[256];
  const int tid  = threadIdx.x;
  const int lane = tid & 63;
  const int wv   = tid >> 6;
  const int row0 = blockIdx.x * 128;

  sstats[tid] = 0.f;

  // ---- stage WT and A ----
#pragma unroll
  for (int c = 0; c < 8; ++c) {
    int gidx = (wv * 8 + c) * 64 + lane;
    int row = gidx >> 4, gL = gidx & 15;
    int gS = (gL & 8) | ((gL & 7) ^ (row & 7));
    const u16* gsrcB = WT + (size_t)row * DD + gS * 8;
    u16* ldstB = lds_b + (size_t)(wv * 8 + c) * 512;
    __builtin_amdgcn_global_load_lds(
        (const __attribute__((address_space(1))) unsigned int*)gsrcB,
        (__attribute__((address_space(3))) unsigned int*)ldstB, 16, 0, 0);
    if (MODE != 2) {
      int arow = row0 + row; if (arow >= NN) arow = NN - 1;
      const u16* gsrcA = (const u16*)Ain + (size_t)arow * DD + gS * 8;
      u16* ldstA = lds_a + (size_t)(wv * 8 + c) * 512;
      __builtin_amdgcn_global_load_lds(
          (const __attribute__((address_space(1))) unsigned int*)gsrcA,
          (__attribute__((address_space(3))) unsigned int*)ldstA, 16, 0, 0);
    }
  }
  if (MODE == 2) {
    const float2* Af = (const float2*)Ain;       // row = 64 float2 (128 f32)
#pragma unroll
    for (int k = 0; k < 32; ++k) {
      int idx = k * 256 + tid;                   // 0..8191
      int r = idx >> 6, ln = idx & 63;
      int n = row0 + r; if (n >= NN) n = NN - 1;
      float2 v = Af[(size_t)n * 64 + ln];
      unsigned pk = (unsigned)f2b(v.x) | ((unsigned)f2b(v.y) << 16);
      int gLn = ln >> 2, oin = (ln & 3) * 4;
      int gS = (gLn & 8) | ((gLn & 7) ^ (r & 7));
      *(unsigned*)((char*)lds_a + r * 256 + gS * 16 + oin) = pk;
    }
  }
  __syncthreads();

  const int colid = lane & 15;
  const int lgrp  = lane >> 4;
  const int rowbase = wv * 32;
  const int o = (lgrp & 1) * 8;

  // ---- A fragments for this wave's 32 rows ----
  s16x8 afr[2][4];
#pragma unroll
  for (int rf = 0; rf < 2; ++rf) {
    int r = rowbase + rf * 16 + colid;
    int rb = r << 8, xr = r & 7;
#pragma unroll
    for (int ks = 0; ks < 4; ++ks) {
      int g0 = ks * 4 + (lgrp >> 1);
      uint2 lo = *(const uint2*)((const char*)lds_a + swz_addr(rb, xr, g0, o));
      uint2 hi = *(const uint2*)((const char*)lds_a + swz_addr(rb, xr, g0 + 2, o));
      union { unsigned u[4]; s16x8 v; } pk;
      pk.u[0] = lo.x; pk.u[1] = lo.y; pk.u[2] = hi.x; pk.u[3] = hi.y;
      afr[rf][ks] = pk.v;
    }
  }

  // ext A fragments: k=0..3 = agg4[row] on lgrp==0 lanes (MODE 0/2)
  s16x8 aext[2];
  if (MODE != 1) {
#pragma unroll
    for (int rf = 0; rf < 2; ++rf) {
      int r = row0 + rowbase + rf * 16 + colid;
      if (r >= NN) r = NN - 1;
      float4 a4 = agg4[r];
      union { unsigned u[4]; s16x8 v; } pk;
      pk.u[0] = (lgrp == 0) ? ((unsigned)f2b(a4.x) | ((unsigned)f2b(a4.y) << 16)) : 0u;
      pk.u[1] = (lgrp == 0) ? ((unsigned)f2b(a4.z) | ((unsigned)f2b(a4.w) << 16)) : 0u;
      pk.u[2] = 0u; pk.u[3] = 0u;
      aext[rf] = pk.v;
    }
  }

  // ---- stage resid into lds_a (overlaps MFMA burst); barrier only needed here ----
  if (MODE == 1) {
    __syncthreads();  // all waves done reading lds_a before overwrite
#pragma unroll
    for (int c = 0; c < 8; ++c) {
      int gidx = (wv * 8 + c) * 64 + lane;
      int row = gidx >> 4, gL = gidx & 15;
      int gS = (gL & 8) | ((gL & 7) ^ (row & 7));
      int arow = row0 + row; if (arow >= NN) arow = NN - 1;
      const u16* gsrcR = resid + (size_t)arow * DD + gS * 8;
      u16* ldstR = lds_a + (size_t)(wv * 8 + c) * 512;
      __builtin_amdgcn_global_load_lds(
          (const __attribute__((address_space(1))) unsigned int*)gsrcR,
          (__attribute__((address_space(3))) unsigned int*)ldstR, 16, 0, 0);
    }
  }

  // ---- compute: all 8 column-fragments in registers ----
  f32x4 acc[2][8];
#pragma unroll
  for (int cf = 0; cf < 8; ++cf) {
    const int col = cf * 16 + colid;
    const float bp = biasP[col];
    acc[0][cf] = (f32x4){bp, bp, bp, bp};
    acc[1][cf] = (f32x4){bp, bp, bp, bp};
    int nb = col << 8, xn = col & 7;
#pragma unroll
    for (int ks = 0; ks < 4; ++ks) {
      int g0 = ks * 4 + (lgrp >> 1);
      uint2 lo = *(const uint2*)((const char*)lds_b + swz_addr(nb, xn, g0, o));
      uint2 hi = *(const uint2*)((const char*)lds_b + swz_addr(nb, xn, g0 + 2, o));
      union { unsigned u[4]; s16x8 v; } pk;
      pk.u[0] = lo.x; pk.u[1] = lo.y; pk.u[2] = hi.x; pk.u[3] = hi.y;
      acc[0][cf] = __builtin_amdgcn_mfma_f32_16x16x32_bf16(afr[0][ks], pk.v, acc[0][cf], 0, 0, 0);
      acc[1][cf] = __builtin_amdgcn_mfma_f32_16x16x32_bf16(afr[1][ks], pk.v, acc[1][cf], 0, 0, 0);
    }
    if (MODE != 1) {
      union { unsigned u[4]; s16x8 v; } bx;
      if (lgrp == 0) {
        float w0 = w_e2l[col], w1 = w_e2l[DD + col];
        float w2 = w_e2l[2 * DD + col], be = b_e2l[col];
        bx.u[0] = (unsigned)f2b(w0) | ((unsigned)f2b(w1) << 16);
        bx.u[1] = (unsigned)f2b(w2) | ((unsigned)f2b(be) << 16);
      } else { bx.u[0] = 0u; bx.u[1] = 0u; }
      bx.u[2] = 0u; bx.u[3] = 0u;
      acc[0][cf] = __builtin_amdgcn_mfma_f32_16x16x32_bf16(aext[0], bx.v, acc[0][cf], 0, 0, 0);
      acc[1][cf] = __builtin_amdgcn_mfma_f32_16x16x32_bf16(aext[1], bx.v, acc[1][cf], 0, 0, 0);
    }
  }
  __syncthreads();  // resid arrived (vmcnt drained by barrier); all B reads done

  // ---- epilogue: extra + relu + stats, staged into lds_b ----
#pragma unroll
  for (int cf = 0; cf < 8; ++cf) {
    const int col = cf * 16 + colid;
    float sc, sh;
    if (MODE == 1) { sc = rese[col]; sh = rese[DD + col]; }
    float s = 0.f, s2 = 0.f;
    int gc = col >> 3, cb = (col & 7) * 2;
#pragma unroll
    for (int rf = 0; rf < 2; ++rf)
#pragma unroll
      for (int q = 0; q < 4; ++q) {
        int rloc = rowbase + rf * 16 + lgrp * 4 + q;
        int r = row0 + rloc;
        float v = acc[rf][cf][q];
        if (MODE == 1) {
          int gsr = (gc & 8) | ((gc & 7) ^ (rloc & 7));
          u16 rv = *(const u16*)((const char*)lds_a + rloc * 256 + gsr * 16 + cb);
          v += sc * b2f(rv) + sh;
        }
        v = fmaxf(v, 0.f);
        if (r < NN) { s += v; s2 += v * v; }
        int gso = (gc & 8) | ((gc & 7) ^ (rloc & 7));
        *(u16*)((char*)lds_b + rloc * 256 + gso * 16 + cb) = f2b(v);
      }
    s  += __shfl_xor(s, 16);  s  += __shfl_xor(s, 32);
    s2 += __shfl_xor(s2, 16); s2 += __shfl_xor(s2, 32);
    if (lgrp == 0) {
      atomicAdd(&sstats[col], s);
      atomicAdd(&sstats[DD + col], s2);
    }
  }
  __syncthreads();

  // ---- coalesced store from lds_b (+ fp8 shadow for gathered buffers) ----
#pragma unroll
  for (int k = 0; k < 8; ++k) {
    int idx = k * 256 + tid;          // 0..2047
    int r = idx >> 4, g = idx & 15;
    if (row0 + r < NN) {
      int gd = (g & 8) | ((g & 7) ^ (r & 7));   // data granule stored at slot g
      uint4 v = *(const uint4*)((const char*)lds_b + r * 256 + g * 16);
      *(uint4*)(out + (size_t)(row0 + r) * DD + gd * 8) = v;
      if (MODE != 0) {
        int p0 = 0, p1 = 0;
        p0 = __builtin_amdgcn_cvt_pk_fp8_f32(blo(v.x), bhi(v.x), p0, false);
        p0 = __builtin_amdgcn_cvt_pk_fp8_f32(blo(v.y), bhi(v.y), p0, true);
        p1 = __builtin_amdgcn_cvt_pk_fp8_f32(blo(v.z), bhi(v.z), p1, false);
        p1 = __builtin_amdgcn_cvt_pk_fp8_f32(blo(v.w), bhi(v.w), p1, true);
        uint2 o8; o8.x = (unsigned)p0; o8.y = (unsigned)p1;
        *(uint2*)(out8 + (size_t)(row0 + r) * DD + gd * 8) = o8;
      }
    }
  }
  atomicAdd(&stats_out[(blockIdx.x & (NCOPY - 1)) * 256 + tid], sstats[tid]);
}

// ---------------- segment max (bf16 input) ----------------
__global__ void k_segmax(const u16* __restrict__ R, const int* __restrict__ g_idx,
                         unsigned* __restrict__ gemb_enc,
                         const float* __restrict__ stats, const float* __restrict__ g,
                         const float* __restrict__ b) {
  int t = blockIdx.x * blockDim.x + threadIdx.x;
  int d = t & (DD - 1);
  int chunk = t >> 7;
  int n0 = chunk * 8;
  if (n0 >= NN) return;
  float mean = stats[d] * (1.f / NN);
  float var  = stats[DD + d] * (1.f / NN) - mean * mean;
  float rs = rsqrtf(var + BN_EPS);
  float scale = g[d] * rs;
  float shift = b[d] - mean * scale;
  int cur = -1; float run = 0.f;
  int nend = n0 + 8; if (nend > NN) nend = NN;
  for (int n = n0; n < nend; ++n) {
    float v = scale * b2f(R[(size_t)n * DD + d]) + shift;
    int gi = g_idx[n];
    if (gi != cur) {
      if (cur >= 0) atomicMax(&gemb_enc[cur * DD + d], enc_f(run));
      cur = gi; run = v;
    } else {
      run = fmaxf(run, v);
    }
  }
  if (cur >= 0) atomicMax(&gemb_enc[cur * DD + d], enc_f(run));
}

// ---------------- readout ----------------
__global__ void k_readout(const unsigned* __restrict__ gemb,
                          const float* __restrict__ W, const float* __restrict__ b,
                          float* __restrict__ out) {
  __shared__ float row[DD];
  int g = blockIdx.x, t = threadIdx.x;
  row[t] = dec_f(gemb[g * DD + t]);
  __syncthreads();
  float acc = b[t];
  for (int d = 0; d < DD; ++d) acc += row[d] * W[d * DD + t];
  out[g * DD + t] = fmaxf(acc, 0.f);
}

extern "C" void kernel_launch(void* const* d_in, const int* in_sizes, int n_in,
                              void* d_out, int out_size, void* d_ws, size_t ws_size,
                              hipStream_t stream) {
  const float* node_feat = (const float*)d_in[0];
  const float* edge_feat = (const float*)d_in[1];
  const int*   efrom     = (const int*)d_in[2];
  const int*   eto       = (const int*)d_in[3];
  const int*   g_idx     = (const int*)d_in[4];
  const float* w_n2l_w   = (const float*)d_in[6];
  const float* w_n2l_b   = (const float*)d_in[7];
  const float* w_e2l_w   = (const float*)d_in[8];   // [4][3][128]
  const float* w_e2l_b   = (const float*)d_in[9];   // [4][128]
  const float* conv_w    = (const float*)d_in[10];  // [3][128][128]
  const float* conv_b    = (const float*)d_in[11];
  const float* l2_w      = (const float*)d_in[12];
  const float* l2_b      = (const float*)d_in[13];
  const float* msg_bn_g  = (const float*)d_in[14];  // [4][128]
  const float* msg_bn_b  = (const float*)d_in[15];
  const float* hid_bn_g  = (const float*)d_in[16];  // [3][128]
  const float* hid_bn_b  = (const float*)d_in[17];
  const float* readout_w = (const float*)d_in[18];
  const float* readout_b = (const float*)d_in[19];
  float* out = (float*)d_out;
  (void)in_sizes; (void)n_in; (void)out_size; (void)ws_size;

  char* ws = (char*)d_ws;
  size_t off = 0;
  auto alloc = [&](size_t bytes) -> void* {
    void* p = ws + off; off += (bytes + 511) & ~(size_t)511; return p;
  };
  u16*      Pb0     = (u16*)alloc((size_t)NN * DD * 2);
  u16*      Pb1     = (u16*)alloc((size_t)NN * DD * 2);
  u16*      Pb2     = (u16*)alloc((size_t)NN * DD * 2);   // also CSR staging scratch
  u8*       P8a     = (u8*)alloc((size_t)NN * DD);        // fp8 shadow of Pb0-chain
  u8*       P8b     = (u8*)alloc((size_t)NN * DD);        // fp8 shadow of Pb1-chain
  float*    agg4    = (float*)alloc((size_t)NN * 4 * 4);
  int*      row_ptr = (int*)alloc((size_t)(NN + 1) * 4);
  int*      csr_src = (int*)alloc((size_t)NE * 4);
  int*      S       = (int*)alloc((size_t)NBKT * NBLK_A * 4);  // 204800
  int*      bsumA   = (int*)alloc((size_t)256 * 4);
  int*      boffA   = (int*)alloc((size_t)256 * 4);
  float*    stats   = (float*)alloc((size_t)7 * NCOPY * 256 * 4);  // raw copies
  float*    statfin = (float*)alloc((size_t)4 * 256 * 4);          // finalized msg stats
  unsigned* gemb    = (unsigned*)alloc((size_t)GG * DD * 4);
  u16*      wt[7];
  float*    bp[7];
  float*    re[7];
  for (int i = 0; i < 7; ++i) {
    wt[i] = (u16*)alloc((size_t)DD * DD * 2);
    bp[i] = (float*)alloc((size_t)DD * 4);
    re[i] = (float*)alloc((size_t)2 * DD * 4);
  }
  // CSR staging aliases Pb2 (dead until the first conv GEMM)
  int*   tmp_dst = (int*)Pb2;                       // 6.4 MB
  uint2* tmp_se  = (uint2*)((char*)Pb2 + (size_t)NE * 4);  // 12.8 MB (<= 25.6 total)

  k_init<<<(NN + 255) / 256, 256, 0, stream>>>(stats, statfin, gemb);
  k_histA<<<NBLK_A, 256, 0, stream>>>(eto, S);
  k_scanA1<<<NSCAN, 1024, 0, stream>>>(S, bsumA);
  k_scanA2<<<1, 256, 0, stream>>>(bsumA, boffA);
  k_scanA3<<<NSCAN, 1024, 0, stream>>>(S, boffA);
  k_scatter1<<<NBLK_A, 256, 0, stream>>>(eto, efrom, S, tmp_dst, tmp_se);
  k_sort2<<<NBKT, 256, 0, stream>>>(S, tmp_dst, tmp_se, edge_feat, row_ptr,
                                    csr_src, agg4);
  k_wprep0<<<4, 256, 0, stream>>>(w_n2l_w, w_n2l_b, conv_w, conv_b,
                                  wt[0], bp[0], wt[1], bp[1], wt[3], bp[3], wt[5], bp[5]);

  // raw stat buffers: [msg0..msg3, hid0..hid2] x (NCOPY*256)
  float* msg_raw[4] = { stats + 0*NCOPY*256, stats + 1*NCOPY*256,
                        stats + 2*NCOPY*256, stats + 3*NCOPY*256 };
  float* hid_raw[3] = { stats + 4*NCOPY*256, stats + 5*NCOPY*256, stats + 6*NCOPY*256 };
  float* msg_fin[4] = { statfin, statfin + 256, statfin + 512, statfin + 768 };
  const int GEMM_GRID = (NN + 127) / 128;  // 782

  // GEMM0 (MODE 2): Pb0 = relu(bf16(node_feat) @ w_n2l + b + e2n0); fp8 shadow P8a
  k_gemm<2><<<GEMM_GRID, 256, 0, stream>>>(node_feat, wt[0], bp[0], Pb0, P8a, msg_raw[0],
      nullptr, nullptr, (const float4*)agg4, w_e2l_w + 0 * 3 * DD, w_e2l_b + 0 * DD);
  k_redstat<<<1, 256, 0, stream>>>(msg_raw[0], msg_fin[0]);

  u16* R = Pb0; u16* other = Pb1;
  u8*  R8 = P8a; u8* other8 = P8b;
  for (int lv = 0; lv < 3; ++lv) {
    int wc = 1 + 2 * lv, wl = 2 + 2 * lv;
    // agg = affine_msg[lv](seg(R[from])) -> other (reads fp8 shadow of R)
    k_gather<<<(NN * 64 + 255) / 256, 256, 0, stream>>>(R8, other, row_ptr, csr_src,
        msg_fin[lv], msg_bn_g + lv * DD, msg_bn_b + lv * DD);
    // conv (MODE 0): Pb2 = relu(other @ conv_w[lv] + conv_b + e2n[lv+1]); raw -> hid[lv]
    k_gemm<0><<<GEMM_GRID, 256, 0, stream>>>(other, wt[wc], bp[wc], Pb2, nullptr,
        hid_raw[lv], nullptr, nullptr, (const float4*)agg4,
        w_e2l_w + (size_t)(lv + 1) * 3 * DD, w_e2l_b + (lv + 1) * DD);
    // l2 (MODE 1): other = relu(norm_hid(Pb2) @ l2_w[lv] + l2_b + affine_msg[lv](R))
    k_wprep1<<<1, 256, 0, stream>>>(l2_w + (size_t)lv * DD * DD, l2_b + lv * DD,
        hid_raw[lv], hid_bn_g + lv * DD, hid_bn_b + lv * DD,
        msg_raw[lv], msg_bn_g + lv * DD, msg_bn_b + lv * DD, wt[wl], bp[wl], re[wl]);
    k_gemm<1><<<GEMM_GRID, 256, 0, stream>>>(Pb2, wt[wl], bp[wl], other, other8,
        msg_raw[lv + 1], re[wl], R, nullptr, nullptr, nullptr);
    k_redstat<<<1, 256, 0, stream>>>(msg_raw[lv + 1], msg_fin[lv + 1]);
    u16* t = R; R = other; other = t;
    u8*  t8 = R8; R8 = other8; other8 = t8;
  }

  k_segmax<<<(NN / 8) * DD / 256, 256, 0, stream>>>(
      R, g_idx, gemb, msg_fin[3], msg_bn_g + 3 * DD, msg_bn_b + 3 * DD);
  k_readout<<<GG, DD, 0, stream>>>(gemb, readout_w, readout_b, out);
}

// Round 19
// 537.868 us; speedup vs baseline: 1.0606x; 1.0251x over previous
//
#include <hip/hip_runtime.h>
#include <hip/hip_bf16.h>

#define NN 100000
#define NE 1600000
#define DD 128
#define GG 64
#define BN_EPS 1e-5f
#define NCOPY 16

#define NBKT 512
#define NPB 196            // nodes per bucket (512*196 = 100352 >= NN)
#define NBLK_A 400
#define EPB 4000           // edges per histogram/scatter block (400*4000 = NE)
#define NSCAN (NBKT * NBLK_A / 1024)   // 200 scan blocks

typedef unsigned short u16;
typedef unsigned char u8;
using f32x4 = __attribute__((ext_vector_type(4))) float;
using f32x2 = __attribute__((ext_vector_type(2))) float;
using s16x8 = __attribute__((ext_vector_type(8))) short;

__device__ __forceinline__ unsigned enc_f(float v) {
  unsigned u = __float_as_uint(v);
  return (u & 0x80000000u) ? ~u : (u | 0x80000000u);
}
__device__ __forceinline__ float dec_f(unsigned k) {
  unsigned u = (k & 0x80000000u) ? (k & 0x7FFFFFFFu) : ~k;
  return __uint_as_float(u);
}
__device__ __forceinline__ u16 f2b(float x) {
  __hip_bfloat16 h = __float2bfloat16(x);
  return *(u16*)&h;
}
__device__ __forceinline__ float b2f(u16 u) {
  unsigned v = ((unsigned)u) << 16;
  return __uint_as_float(v);
}
__device__ __forceinline__ float blo(unsigned v) { return __uint_as_float(v << 16); }
__device__ __forceinline__ float bhi(unsigned v) { return __uint_as_float(v & 0xFFFF0000u); }

// ---------------- init ----------------
__global__ void k_init(float* stats_raw, float* stats_fin, unsigned* gemb_enc) {
  int i = blockIdx.x * blockDim.x + threadIdx.x;
  if (i < 7 * NCOPY * 256) stats_raw[i] = 0.f;
  if (i < 4 * 256) stats_fin[i] = 0.f;
  if (i < GG*DD) gemb_enc[i] = 0x007FFFFFu;  // enc(-inf)
}

// ---------------- CSR build, level 1: per-block bucket histogram ----------------
__global__ void k_histA(const int* __restrict__ to, int* __restrict__ bh) {
  __shared__ int h[NBKT];
  int t = threadIdx.x, b = blockIdx.x;
  for (int j = t; j < NBKT; j += 256) h[j] = 0;
  __syncthreads();
  int e0 = b * EPB;
  for (int i = t; i < EPB; i += 256) {
    int e = e0 + i;
    if (e < NE) atomicAdd(&h[to[e] / NPB], 1);
  }
  __syncthreads();
  for (int j = t; j < NBKT; j += 256) bh[j * NBLK_A + b] = h[j];
}

// ---------------- scan of NBKT*NBLK_A (bucket,block) counts ----------------
__global__ void k_scanA1(int* data, int* bsum) {   // NSCAN blocks x 1024
  __shared__ int lds[1024];
  int t = threadIdx.x, i = blockIdx.x * 1024 + t;
  int v = data[i];
  lds[t] = v;
  __syncthreads();
  for (int off = 1; off < 1024; off <<= 1) {
    int a = (t >= off) ? lds[t - off] : 0;
    __syncthreads();
    lds[t] += a;
    __syncthreads();
  }
  data[i] = lds[t] - v;
  if (t == 1023) bsum[blockIdx.x] = lds[t];
}

__global__ void k_scanA2(const int* __restrict__ bsum, int* boff) {  // 1 block x 256
  __shared__ int lds[256];
  int t = threadIdx.x;
  int v = (t < NSCAN) ? bsum[t] : 0;
  lds[t] = v;
  __syncthreads();
  for (int off = 1; off < 256; off <<= 1) {
    int a = (t >= off) ? lds[t - off] : 0;
    __syncthreads();
    lds[t] += a;
    __syncthreads();
  }
  if (t < NSCAN) boff[t] = lds[t] - v;
}

__global__ void k_scanA3(int* data, const int* __restrict__ boff) {  // NSCAN x 1024
  int i = blockIdx.x * 1024 + threadIdx.x;
  data[i] += boff[blockIdx.x];
}

// ---------------- CSR build, level 2: scatter into bucket-major staging (1x 16B store) ----------------
__global__ void k_scatter1(const int* __restrict__ to, const int* __restrict__ from,
                           const int* __restrict__ S, uint4* __restrict__ tmp) {
  __shared__ int cur[NBKT];
  int t = threadIdx.x, b = blockIdx.x;
  for (int j = t; j < NBKT; j += 256) cur[j] = S[j * NBLK_A + b];
  __syncthreads();
  int e0 = b * EPB;
  for (int i = t; i < EPB; i += 256) {
    int e = e0 + i;
    if (e < NE) {
      int n = to[e];
      int p = atomicAdd(&cur[n / NPB], 1);
      tmp[p] = make_uint4((unsigned)n, (unsigned)from[e], (unsigned)e, 0u);
    }
  }
}

// ---------------- CSR build, level 3: per-bucket counting sort -> row_ptr + csr_src
//                  + fused per-node edge-feature aggregation -> agg4 ----------------
__global__ __launch_bounds__(256)
void k_sort2(const int* __restrict__ S, const uint4* __restrict__ tmp,
             const float* __restrict__ ef,
             int* __restrict__ row_ptr, int* __restrict__ csr_src,
             float* __restrict__ agg4) {
  __shared__ int hist[NPB];
  __shared__ int tsum[256];
  __shared__ float ag0[NPB], ag1[NPB], ag2[NPB];
  const int k = blockIdx.x, t = threadIdx.x;
  const int base = k * NPB;
  const int lo = S[k * NBLK_A];
  const int hi = (k == NBKT - 1) ? NE : S[(k + 1) * NBLK_A];
  if (t < NPB) { hist[t] = 0; ag0[t] = 0.f; ag1[t] = 0.f; ag2[t] = 0.f; }
  __syncthreads();
  for (int i = lo + t; i < hi; i += 256)
    atomicAdd(&hist[(int)tmp[i].x - base], 1);
  __syncthreads();
  int v = (t < NPB) ? hist[t] : 0;
  tsum[t] = v;
  __syncthreads();
  for (int off = 1; off < 256; off <<= 1) {
    int a = (t >= off) ? tsum[t - off] : 0;
    __syncthreads();
    tsum[t] += a;
    __syncthreads();
  }
  int e0 = lo + tsum[t] - v;
  __syncthreads();
  if (t < NPB) {
    hist[t] = e0;
    if (base + t < NN) row_ptr[base + t] = e0;
  }
  if (k == NBKT - 1 && t == 0) row_ptr[NN] = NE;
  __syncthreads();
  for (int i = lo + t; i < hi; i += 256) {
    uint4 se = tmp[i];
    int n = (int)se.x;
    int p = atomicAdd(&hist[n - base], 1);
    csr_src[p] = (int)se.y;
    size_t eb = (size_t)se.z * 3;
    atomicAdd(&ag0[n - base], ef[eb + 0]);
    atomicAdd(&ag1[n - base], ef[eb + 1]);
    atomicAdd(&ag2[n - base], ef[eb + 2]);
  }
  __syncthreads();
  if (t < NPB && base + t < NN)
    ((float4*)agg4)[base + t] = make_float4(ag0[t], ag1[t], ag2[t], (float)v);
}

// ---------------- reduce 16 stat copies -> finalized 256 floats ----------------
__global__ void k_redstat(const float* __restrict__ raw, float* __restrict__ fin) {
  int c = threadIdx.x;  // 256
  float s = 0.f;
#pragma unroll
  for (int i = 0; i < NCOPY; ++i) s += raw[i * 256 + c];
  fin[c] = s;
}

// ---------------- neighbor gather: fp8 rows, 4 edges/instr, 8 dims/lane ----------------
__global__ __launch_bounds__(256)
void k_gather(const u8* __restrict__ R8, u16* __restrict__ out,
              const int* __restrict__ row_ptr, const int* __restrict__ csr_src,
              const float* __restrict__ stats, const float* __restrict__ g,
              const float* __restrict__ b) {
  const int wid = (blockIdx.x * 256 + threadIdx.x) >> 6;   // node
  if (wid >= NN) return;
  const int lane = threadIdx.x & 63;
  const int esel = lane >> 4;          // edge slot 0..3
  const int dpos = lane & 15;          // uint2 slot = 8 fp8 dims
  const int s = row_ptr[wid], e = row_ptr[wid + 1];
  const uint2* R2 = (const uint2*)R8;  // row = 16 uint2 (128 fp8)
  f32x2 a01 = {0.f, 0.f}, a23 = {0.f, 0.f}, a45 = {0.f, 0.f}, a67 = {0.f, 0.f};
#define ACC(V)                                                        \
  a01 += __builtin_amdgcn_cvt_pk_f32_fp8((int)V.x, false);            \
  a23 += __builtin_amdgcn_cvt_pk_f32_fp8((int)V.x, true);             \
  a45 += __builtin_amdgcn_cvt_pk_f32_fp8((int)V.y, false);            \
  a67 += __builtin_amdgcn_cvt_pk_f32_fp8((int)V.y, true);
  int i = s;
  for (; i + 15 < e; i += 16) {
    int q0 = csr_src[i      + esel];
    int q1 = csr_src[i + 4  + esel];
    int q2 = csr_src[i + 8  + esel];
    int q3 = csr_src[i + 12 + esel];
    uint2 w0 = R2[(size_t)q0 * 16 + dpos];
    uint2 w1 = R2[(size_t)q1 * 16 + dpos];
    uint2 w2 = R2[(size_t)q2 * 16 + dpos];
    uint2 w3 = R2[(size_t)q3 * 16 + dpos];
    ACC(w0) ACC(w1) ACC(w2) ACC(w3)
  }
  for (; i + 3 < e; i += 4) {
    int q = csr_src[i + esel];
    uint2 wv = R2[(size_t)q * 16 + dpos];
    ACC(wv)
  }
  if (i < e && esel < e - i) {         // tail 1..3 edges
    int q = csr_src[i + esel];
    uint2 wv = R2[(size_t)q * 16 + dpos];
    ACC(wv)
  }
#undef ACC
  float a[8] = {a01.x, a01.y, a23.x, a23.y, a45.x, a45.y, a67.x, a67.y};
#pragma unroll
  for (int j = 0; j < 8; ++j) {
    a[j] += __shfl_xor(a[j], 16);
    a[j] += __shfl_xor(a[j], 32);
  }
  if (esel == 0) {
    const int d0 = dpos * 8;
    float dg = (float)(e - s);
    unsigned pk[4];
#pragma unroll
    for (int h = 0; h < 4; ++h) {
      float r[2];
#pragma unroll
      for (int j = 0; j < 2; ++j) {
        int d = d0 + h * 2 + j;
        float m  = stats[d] * (1.f / NN);
        float vv = stats[DD + d] * (1.f / NN) - m * m;
        float sc = g[d] * rsqrtf(vv + BN_EPS);
        float sh = b[d] - m * sc;
        r[j] = sc * a[h * 2 + j] + sh * dg;
      }
      pk[h] = (unsigned)f2b(r[0]) | ((unsigned)f2b(r[1]) << 16);
    }
    uint4 v; v.x = pk[0]; v.y = pk[1]; v.z = pk[2]; v.w = pk[3];
    ((uint4*)out)[(size_t)wid * 16 + dpos] = v;
  }
}

// ---------------- weight prep ----------------
// MODE 1: in_stats/res_stats are RAW (NCOPY copies) — summed here.
template<int MODE>
__device__ __forceinline__ void wprep_body(
    const float* __restrict__ W, const float* __restrict__ bias,
    const float* __restrict__ in_stats, const float* __restrict__ in_g,
    const float* __restrict__ in_b,
    const float* __restrict__ res_stats, const float* __restrict__ res_g,
    const float* __restrict__ res_b,
    u16* __restrict__ WT, float* __restrict__ biasP, float* __restrict__ rese) {
  __shared__ float s_s[DD], s_t[DD];
  int t = threadIdx.x;
  if (t < DD) {
    float s = 1.f, tt = 0.f;
    if (MODE == 1) {
      float s1 = 0.f, s2 = 0.f, r1 = 0.f, r2 = 0.f;
#pragma unroll
      for (int i = 0; i < NCOPY; ++i) {
        s1 += in_stats[i * 256 + t];
        s2 += in_stats[i * 256 + DD + t];
        r1 += res_stats[i * 256 + t];
        r2 += res_stats[i * 256 + DD + t];
      }
      float mean = s1 * (1.f / NN);
      float var  = s2 * (1.f / NN) - mean * mean;
      float rs = rsqrtf(var + BN_EPS);
      s = in_g[t] * rs;
      tt = in_b[t] - mean * s;
      float m2 = r1 * (1.f / NN);
      float v2 = r2 * (1.f / NN) - m2 * m2;
      float rr = rsqrtf(v2 + BN_EPS);
      float sc = res_g[t] * rr;
      rese[t] = sc;
      rese[DD + t] = res_b[t] - m2 * sc;
    }
    s_s[t] = s; s_t[t] = tt;
  }
  __syncthreads();
  for (int idx = t; idx < DD * DD; idx += 256) {
    int k = idx >> 7, n = idx & 127;
    WT[n * DD + k] = f2b(W[idx] * s_s[k]);
  }
  if (t < DD) {
    float acc = bias[t];
    if (MODE == 1)
      for (int k = 0; k < DD; ++k) acc += s_t[k] * W[k * DD + t];
    biasP[t] = acc;
  }
}

__global__ void k_wprep0(const float* __restrict__ w_n2l_w, const float* __restrict__ w_n2l_b,
                         const float* __restrict__ conv_w, const float* __restrict__ conv_b,
                         u16* wt0, float* bp0, u16* wt1, float* bp1,
                         u16* wt3, float* bp3, u16* wt5, float* bp5) {
  int blk = blockIdx.x;
  const float* W; const float* bias; u16* WT; float* biasP;
  if (blk == 0)      { W = w_n2l_w;              bias = w_n2l_b;          WT = wt0; biasP = bp0; }
  else if (blk == 1) { W = conv_w;               bias = conv_b;           WT = wt1; biasP = bp1; }
  else if (blk == 2) { W = conv_w + DD * DD;     bias = conv_b + DD;      WT = wt3; biasP = bp3; }
  else               { W = conv_w + 2 * DD * DD; bias = conv_b + 2 * DD;  WT = wt5; biasP = bp5; }
  wprep_body<0>(W, bias, nullptr, nullptr, nullptr, nullptr, nullptr, nullptr,
                WT, biasP, nullptr);
}

__global__ void k_wprep1(const float* __restrict__ W, const float* __restrict__ bias,
                         const float* __restrict__ in_stats, const float* __restrict__ in_g,
                         const float* __restrict__ in_b,
                         const float* __restrict__ res_stats, const float* __restrict__ res_g,
                         const float* __restrict__ res_b,
                         u16* WT, float* biasP, float* rese) {
  wprep_body<1>(W, bias, in_stats, in_g, in_b, res_stats, res_g, res_b, WT, biasP, rese);
}

// swizzled LDS byte address: granule XOR within 8-granule (128B) halves of a 256B row
__device__ __forceinline__ int swz_addr(int row_bytes, int xr, int g, int o) {
  return row_bytes + ((((g & 7) ^ xr) | (g & 8)) << 4) + o;
}

// ---------------- MFMA GEMM, 128-row tiles, LDS-staged epilogue (round-13 structure) ----------------
// MODE 0: A bf16 (global_load_lds); e2n via K-extension MFMA from agg4/w_e2l
// MODE 1: A bf16 (global_load_lds); extra = affine(resid); writes fp8 shadow
// MODE 2: A fp32, on-the-fly bf16 cvt; e2n via K-extension MFMA; writes fp8 shadow
template<int MODE>
__global__ __launch_bounds__(256, 2)
void k_gemm(const void* __restrict__ Ain, const u16* __restrict__ WT,
            const float* __restrict__ biasP, u16* __restrict__ out,
            u8* __restrict__ out8,
            float* __restrict__ stats_out,
            const float* __restrict__ rese, const u16* __restrict__ resid,
            const float4* __restrict__ agg4,
            const float* __restrict__ w_e2l, const float* __restrict__ b_e2l) {
  __shared__ __align__(16) u16 lds_a[128 * 128];   // A (swz) -> resid (MODE1)
  __shared__ __align__(16) u16 lds_b[128 * 128];   // WT (swz) -> out staging
  __shared__ float sstats[256];
  const int tid  = threadIdx.x;
  const int lane = tid & 63;
  const int wv   = tid >> 6;
  const int row0 = blockIdx.x * 128;

  sstats[tid] = 0.f;

  // ---- stage WT and A ----
#pragma unroll
  for (int c = 0; c < 8; ++c) {
    int gidx = (wv * 8 + c) * 64 + lane;
    int row = gidx >> 4, gL = gidx & 15;
    int gS = (gL & 8) | ((gL & 7) ^ (row & 7));
    const u16* gsrcB = WT + (size_t)row * DD + gS * 8;
    u16* ldstB = lds_b + (size_t)(wv * 8 + c) * 512;
    __builtin_amdgcn_global_load_lds(
        (const __attribute__((address_space(1))) unsigned int*)gsrcB,
        (__attribute__((address_space(3))) unsigned int*)ldstB, 16, 0, 0);
    if (MODE != 2) {
      int arow = row0 + row; if (arow >= NN) arow = NN - 1;
      const u16* gsrcA = (const u16*)Ain + (size_t)arow * DD + gS * 8;
      u16* ldstA = lds_a + (size_t)(wv * 8 + c) * 512;
      __builtin_amdgcn_global_load_lds(
          (const __attribute__((address_space(1))) unsigned int*)gsrcA,
          (__attribute__((address_space(3))) unsigned int*)ldstA, 16, 0, 0);
    }
  }
  if (MODE == 2) {
    const float2* Af = (const float2*)Ain;       // row = 64 float2 (128 f32)
#pragma unroll
    for (int k = 0; k < 32; ++k) {
      int idx = k * 256 + tid;                   // 0..8191
      int r = idx >> 6, ln = idx & 63;
      int n = row0 + r; if (n >= NN) n = NN - 1;
      float2 v = Af[(size_t)n * 64 + ln];
      unsigned pk = (unsigned)f2b(v.x) | ((unsigned)f2b(v.y) << 16);
      int gLn = ln >> 2, oin = (ln & 3) * 4;
      int gS = (gLn & 8) | ((gLn & 7) ^ (r & 7));
      *(unsigned*)((char*)lds_a + r * 256 + gS * 16 + oin) = pk;
    }
  }
  __syncthreads();

  const int colid = lane & 15;
  const int lgrp  = lane >> 4;
  const int rowbase = wv * 32;
  const int o = (lgrp & 1) * 8;

  // ---- A fragments for this wave's 32 rows ----
  s16x8 afr[2][4];
#pragma unroll
  for (int rf = 0; rf < 2; ++rf) {
    int r = rowbase + rf * 16 + colid;
    int rb = r << 8, xr = r & 7;
#pragma unroll
    for (int ks = 0; ks < 4; ++ks) {
      int g0 = ks * 4 + (lgrp >> 1);
      uint2 lo = *(const uint2*)((const char*)lds_a + swz_addr(rb, xr, g0, o));
      uint2 hi = *(const uint2*)((const char*)lds_a + swz_addr(rb, xr, g0 + 2, o));
      union { unsigned u[4]; s16x8 v; } pk;
      pk.u[0] = lo.x; pk.u[1] = lo.y; pk.u[2] = hi.x; pk.u[3] = hi.y;
      afr[rf][ks] = pk.v;
    }
  }

  // ext A fragments: k=0..3 = agg4[row] on lgrp==0 lanes (MODE 0/2)
  s16x8 aext[2];
  if (MODE != 1) {
#pragma unroll
    for (int rf = 0; rf < 2; ++rf) {
      int r = row0 + rowbase + rf * 16 + colid;
      if (r >= NN) r = NN - 1;
      float4 a4 = agg4[r];
      union { unsigned u[4]; s16x8 v; } pk;
      pk.u[0] = (lgrp == 0) ? ((unsigned)f2b(a4.x) | ((unsigned)f2b(a4.y) << 16)) : 0u;
      pk.u[1] = (lgrp == 0) ? ((unsigned)f2b(a4.z) | ((unsigned)f2b(a4.w) << 16)) : 0u;
      pk.u[2] = 0u; pk.u[3] = 0u;
      aext[rf] = pk.v;
    }
  }

  // ---- stage resid into lds_a (overlaps MFMA burst); barrier only needed here ----
  if (MODE == 1) {
    __syncthreads();  // all waves done reading lds_a before overwrite
#pragma unroll
    for (int c = 0; c < 8; ++c) {
      int gidx = (wv * 8 + c) * 64 + lane;
      int row = gidx >> 4, gL = gidx & 15;
      int gS = (gL & 8) | ((gL & 7) ^ (row & 7));
      int arow = row0 + row; if (arow >= NN) arow = NN - 1;
      const u16* gsrcR = resid + (size_t)arow * DD + gS * 8;
      u16* ldstR = lds_a + (size_t)(wv * 8 + c) * 512;
      __builtin_amdgcn_global_load_lds(
          (const __attribute__((address_space(1))) unsigned int*)gsrcR,
          (__attribute__((address_space(3))) unsigned int*)ldstR, 16, 0, 0);
    }
  }

  // ---- compute: all 8 column-fragments in registers ----
  f32x4 acc[2][8];
#pragma unroll
  for (int cf = 0; cf < 8; ++cf) {
    const int col = cf * 16 + colid;
    const float bp = biasP[col];
    acc[0][cf] = (f32x4){bp, bp, bp, bp};
    acc[1][cf] = (f32x4){bp, bp, bp, bp};
    int nb = col << 8, xn = col & 7;
#pragma unroll
    for (int ks = 0; ks < 4; ++ks) {
      int g0 = ks * 4 + (lgrp >> 1);
      uint2 lo = *(const uint2*)((const char*)lds_b + swz_addr(nb, xn, g0, o));
      uint2 hi = *(const uint2*)((const char*)lds_b + swz_addr(nb, xn, g0 + 2, o));
      union { unsigned u[4]; s16x8 v; } pk;
      pk.u[0] = lo.x; pk.u[1] = lo.y; pk.u[2] = hi.x; pk.u[3] = hi.y;
      acc[0][cf] = __builtin_amdgcn_mfma_f32_16x16x32_bf16(afr[0][ks], pk.v, acc[0][cf], 0, 0, 0);
      acc[1][cf] = __builtin_amdgcn_mfma_f32_16x16x32_bf16(afr[1][ks], pk.v, acc[1][cf], 0, 0, 0);
    }
    if (MODE != 1) {
      union { unsigned u[4]; s16x8 v; } bx;
      if (lgrp == 0) {
        float w0 = w_e2l[col], w1 = w_e2l[DD + col];
        float w2 = w_e2l[2 * DD + col], be = b_e2l[col];
        bx.u[0] = (unsigned)f2b(w0) | ((unsigned)f2b(w1) << 16);
        bx.u[1] = (unsigned)f2b(w2) | ((unsigned)f2b(be) << 16);
      } else { bx.u[0] = 0u; bx.u[1] = 0u; }
      bx.u[2] = 0u; bx.u[3] = 0u;
      acc[0][cf] = __builtin_amdgcn_mfma_f32_16x16x32_bf16(aext[0], bx.v, acc[0][cf], 0, 0, 0);
      acc[1][cf] = __builtin_amdgcn_mfma_f32_16x16x32_bf16(aext[1], bx.v, acc[1][cf], 0, 0, 0);
    }
  }
  __syncthreads();  // resid arrived (vmcnt drained by barrier); all B reads done

  // ---- epilogue: extra + relu + stats, staged into lds_b ----
#pragma unroll
  for (int cf = 0; cf < 8; ++cf) {
    const int col = cf * 16 + colid;
    float sc, sh;
    if (MODE == 1) { sc = rese[col]; sh = rese[DD + col]; }
    float s = 0.f, s2 = 0.f;
    int gc = col >> 3, cb = (col & 7) * 2;
#pragma unroll
    for (int rf = 0; rf < 2; ++rf)
#pragma unroll
      for (int q = 0; q < 4; ++q) {
        int rloc = rowbase + rf * 16 + lgrp * 4 + q;
        int r = row0 + rloc;
        float v = acc[rf][cf][q];
        if (MODE == 1) {
          int gsr = (gc & 8) | ((gc & 7) ^ (rloc & 7));
          u16 rv = *(const u16*)((const char*)lds_a + rloc * 256 + gsr * 16 + cb);
          v += sc * b2f(rv) + sh;
        }
        v = fmaxf(v, 0.f);
        if (r < NN) { s += v; s2 += v * v; }
        int gso = (gc & 8) | ((gc & 7) ^ (rloc & 7));
        *(u16*)((char*)lds_b + rloc * 256 + gso * 16 + cb) = f2b(v);
      }
    s  += __shfl_xor(s, 16);  s  += __shfl_xor(s, 32);
    s2 += __shfl_xor(s2, 16); s2 += __shfl_xor(s2, 32);
    if (lgrp == 0) {
      atomicAdd(&sstats[col], s);
      atomicAdd(&sstats[DD + col], s2);
    }
  }
  __syncthreads();

  // ---- coalesced store from lds_b (+ fp8 shadow for gathered buffers) ----
#pragma unroll
  for (int k = 0; k < 8; ++k) {
    int idx = k * 256 + tid;          // 0..2047
    int r = idx >> 4, g = idx & 15;
    if (row0 + r < NN) {
      int gd = (g & 8) | ((g & 7) ^ (r & 7));   // data granule stored at slot g
      uint4 v = *(const uint4*)((const char*)lds_b + r * 256 + g * 16);
      *(uint4*)(out + (size_t)(row0 + r) * DD + gd * 8) = v;
      if (MODE != 0) {
        int p0 = 0, p1 = 0;
        p0 = __builtin_amdgcn_cvt_pk_fp8_f32(blo(v.x), bhi(v.x), p0, false);
        p0 = __builtin_amdgcn_cvt_pk_fp8_f32(blo(v.y), bhi(v.y), p0, true);
        p1 = __builtin_amdgcn_cvt_pk_fp8_f32(blo(v.z), bhi(v.z), p1, false);
        p1 = __builtin_amdgcn_cvt_pk_fp8_f32(blo(v.w), bhi(v.w), p1, true);
        uint2 o8; o8.x = (unsigned)p0; o8.y = (unsigned)p1;
        *(uint2*)(out8 + (size_t)(row0 + r) * DD + gd * 8) = o8;
      }
    }
  }
  atomicAdd(&stats_out[(blockIdx.x & (NCOPY - 1)) * 256 + tid], sstats[tid]);
}

// ---------------- segment max (bf16 input) ----------------
__global__ void k_segmax(const u16* __restrict__ R, const int* __restrict__ g_idx,
                         unsigned* __restrict__ gemb_enc,
                         const float* __restrict__ stats, const float* __restrict__ g,
                         const float* __restrict__ b) {
  int t = blockIdx.x * blockDim.x + threadIdx.x;
  int d = t & (DD - 1);
  int chunk = t >> 7;
  int n0 = chunk * 8;
  if (n0 >= NN) return;
  float mean = stats[d] * (1.f / NN);
  float var  = stats[DD + d] * (1.f / NN) - mean * mean;
  float rs = rsqrtf(var + BN_EPS);
  float scale = g[d] * rs;
  float shift = b[d] - mean * scale;
  int cur = -1; float run = 0.f;
  int nend = n0 + 8; if (nend > NN) nend = NN;
  for (int n = n0; n < nend; ++n) {
    float v = scale * b2f(R[(size_t)n * DD + d]) + shift;
    int gi = g_idx[n];
    if (gi != cur) {
      if (cur >= 0) atomicMax(&gemb_enc[cur * DD + d], enc_f(run));
      cur = gi; run = v;
    } else {
      run = fmaxf(run, v);
    }
  }
  if (cur >= 0) atomicMax(&gemb_enc[cur * DD + d], enc_f(run));
}

// ---------------- readout ----------------
__global__ void k_readout(const unsigned* __restrict__ gemb,
                          const float* __restrict__ W, const float* __restrict__ b,
                          float* __restrict__ out) {
  __shared__ float row[DD];
  int g = blockIdx.x, t = threadIdx.x;
  row[t] = dec_f(gemb[g * DD + t]);
  __syncthreads();
  float acc = b[t];
  for (int d = 0; d < DD; ++d) acc += row[d] * W[d * DD + t];
  out[g * DD + t] = fmaxf(acc, 0.f);
}

extern "C" void kernel_launch(void* const* d_in, const int* in_sizes, int n_in,
                              void* d_out, int out_size, void* d_ws, size_t ws_size,
                              hipStream_t stream) {
  const float* node_feat = (const float*)d_in[0];
  const float* edge_feat = (const float*)d_in[1];
  const int*   efrom     = (const int*)d_in[2];
  const int*   eto       = (const int*)d_in[3];
  const int*   g_idx     = (const int*)d_in[4];
  const float* w_n2l_w   = (const float*)d_in[6];
  const float* w_n2l_b   = (const float*)d_in[7];
  const float* w_e2l_w   = (const float*)d_in[8];   // [4][3][128]
  const float* w_e2l_b   = (const float*)d_in[9];   // [4][128]
  const float* conv_w    = (const float*)d_in[10];  // [3][128][128]
  const float* conv_b    = (const float*)d_in[11];
  const float* l2_w      = (const float*)d_in[12];
  const float* l2_b      = (const float*)d_in[13];
  const float* msg_bn_g  = (const float*)d_in[14];  // [4][128]
  const float* msg_bn_b  = (const float*)d_in[15];
  const float* hid_bn_g  = (const float*)d_in[16];  // [3][128]
  const float* hid_bn_b  = (const float*)d_in[17];
  const float* readout_w = (const float*)d_in[18];
  const float* readout_b = (const float*)d_in[19];
  float* out = (float*)d_out;
  (void)in_sizes; (void)n_in; (void)out_size; (void)ws_size;

  char* ws = (char*)d_ws;
  size_t off = 0;
  auto alloc = [&](size_t bytes) -> void* {
    void* p = ws + off; off += (bytes + 511) & ~(size_t)511; return p;
  };
  u16*      Pb0     = (u16*)alloc((size_t)NN * DD * 2);
  u16*      Pb1     = (u16*)alloc((size_t)NN * DD * 2);
  u16*      Pb2     = (u16*)alloc((size_t)NN * DD * 2);   // also CSR staging scratch
  u8*       P8a     = (u8*)alloc((size_t)NN * DD);        // fp8 shadow of Pb0-chain
  u8*       P8b     = (u8*)alloc((size_t)NN * DD);        // fp8 shadow of Pb1-chain
  float*    agg4    = (float*)alloc((size_t)NN * 4 * 4);
  int*      row_ptr = (int*)alloc((size_t)(NN + 1) * 4);
  int*      csr_src = (int*)alloc((size_t)NE * 4);
  int*      S       = (int*)alloc((size_t)NBKT * NBLK_A * 4);  // 204800
  int*      bsumA   = (int*)alloc((size_t)256 * 4);
  int*      boffA   = (int*)alloc((size_t)256 * 4);
  float*    stats   = (float*)alloc((size_t)7 * NCOPY * 256 * 4);  // raw copies
  float*    statfin = (float*)alloc((size_t)4 * 256 * 4);          // finalized msg stats
  unsigned* gemb    = (unsigned*)alloc((size_t)GG * DD * 4);
  u16*      wt[7];
  float*    bp[7];
  float*    re[7];
  for (int i = 0; i < 7; ++i) {
    wt[i] = (u16*)alloc((size_t)DD * DD * 2);
    bp[i] = (float*)alloc((size_t)DD * 4);
    re[i] = (float*)alloc((size_t)2 * DD * 4);
  }
  // CSR staging aliases Pb2 (dead until the first conv GEMM): uint4[NE] = 25.6 MB
  uint4* tmp = (uint4*)Pb2;

  k_init<<<(NN + 255) / 256, 256, 0, stream>>>(stats, statfin, gemb);
  k_histA<<<NBLK_A, 256, 0, stream>>>(eto, S);
  k_scanA1<<<NSCAN, 1024, 0, stream>>>(S, bsumA);
  k_scanA2<<<1, 256, 0, stream>>>(bsumA, boffA);
  k_scanA3<<<NSCAN, 1024, 0, stream>>>(S, boffA);
  k_scatter1<<<NBLK_A, 256, 0, stream>>>(eto, efrom, S, tmp);
  k_sort2<<<NBKT, 256, 0, stream>>>(S, tmp, edge_feat, row_ptr, csr_src, agg4);
  k_wprep0<<<4, 256, 0, stream>>>(w_n2l_w, w_n2l_b, conv_w, conv_b,
                                  wt[0], bp[0], wt[1], bp[1], wt[3], bp[3], wt[5], bp[5]);

  // raw stat buffers: [msg0..msg3, hid0..hid2] x (NCOPY*256)
  float* msg_raw[4] = { stats + 0*NCOPY*256, stats + 1*NCOPY*256,
                        stats + 2*NCOPY*256, stats + 3*NCOPY*256 };
  float* hid_raw[3] = { stats + 4*NCOPY*256, stats + 5*NCOPY*256, stats + 6*NCOPY*256 };
  float* msg_fin[4] = { statfin, statfin + 256, statfin + 512, statfin + 768 };
  const int GEMM_GRID = (NN + 127) / 128;  // 782

  // GEMM0 (MODE 2): Pb0 = relu(bf16(node_feat) @ w_n2l + b + e2n0); fp8 shadow P8a
  k_gemm<2><<<GEMM_GRID, 256, 0, stream>>>(node_feat, wt[0], bp[0], Pb0, P8a, msg_raw[0],
      nullptr, nullptr, (const float4*)agg4, w_e2l_w + 0 * 3 * DD, w_e2l_b + 0 * DD);
  k_redstat<<<1, 256, 0, stream>>>(msg_raw[0], msg_fin[0]);

  u16* R = Pb0; u16* other = Pb1;
  u8*  R8 = P8a; u8* other8 = P8b;
  for (int lv = 0; lv < 3; ++lv) {
    int wc = 1 + 2 * lv, wl = 2 + 2 * lv;
    // agg = affine_msg[lv](seg(R[from])) -> other (reads fp8 shadow of R)
    k_gather<<<(NN * 64 + 255) / 256, 256, 0, stream>>>(R8, other, row_ptr, csr_src,
        msg_fin[lv], msg_bn_g + lv * DD, msg_bn_b + lv * DD);
    // conv (MODE 0): Pb2 = relu(other @ conv_w[lv] + conv_b + e2n[lv+1]); raw -> hid[lv]
    k_gemm<0><<<GEMM_GRID, 256, 0, stream>>>(other, wt[wc], bp[wc], Pb2, nullptr,
        hid_raw[lv], nullptr, nullptr, (const float4*)agg4,
        w_e2l_w + (size_t)(lv + 1) * 3 * DD, w_e2l_b + (lv + 1) * DD);
    // l2 (MODE 1): other = relu(norm_hid(Pb2) @ l2_w[lv] + l2_b + affine_msg[lv](R))
    k_wprep1<<<1, 256, 0, stream>>>(l2_w + (size_t)lv * DD * DD, l2_b + lv * DD,
        hid_raw[lv], hid_bn_g + lv * DD, hid_bn_b + lv * DD,
        msg_raw[lv], msg_bn_g + lv * DD, msg_bn_b + lv * DD, wt[wl], bp[wl], re[wl]);
    k_gemm<1><<<GEMM_GRID, 256, 0, stream>>>(Pb2, wt[wl], bp[wl], other, other8,
        msg_raw[lv + 1], re[wl], R, nullptr, nullptr, nullptr);
    k_redstat<<<1, 256, 0, stream>>>(msg_raw[lv + 1], msg_fin[lv + 1]);
    u16* t = R; R = other; other = t;
    u8*  t8 = R8; R8 = other8; other8 = t8;
  }

  k_segmax<<<(NN / 8) * DD / 256, 256, 0, stream>>>(
      R, g_idx, gemb, msg_fin[3], msg_bn_g + 3 * DD, msg_bn_b + 3 * DD);
  k_readout<<<GG, DD, 0, stream>>>(gemb, readout_w, readout_b, out);
}